// Round 5
// baseline (1659.687 us; speedup 1.0000x reference)
//
#include <hip/hip_runtime.h>
#include <hip/hip_bf16.h>

#define BATCH 2
#define SEQ 2048
#define DMODEL 768
#define NHEADS 12
#define NKV 4
#define DHEAD 64
#define WIN 512
#define GLB 64
#define ROWS (BATCH * SEQ)  // 4096
#define MAXJ 576            // max allowed keys per query row

// ---------------------------------------------------------------------------
// 64x64 tiled GEMM, all fp32. C = A[M,K] @ B[K,N].
// KV=false: C[row*N+col].  KV=true: scatter to (B, NKV, SEQ, DHEAD) layout.
// ---------------------------------------------------------------------------
template <bool KV>
__global__ void gemm_f(const float* __restrict__ A, const float* __restrict__ B,
                       float* __restrict__ C, int M, int N, int K) {
    __shared__ float As[16][64 + 1];
    __shared__ float Bs[16][64 + 1];
    const int bm = blockIdx.y * 64, bn = blockIdx.x * 64;
    const int tid = threadIdx.x;
    const int tr = tid >> 4, tc = tid & 15;
    float acc[4][4] = {};
    for (int k0 = 0; k0 < K; k0 += 16) {
#pragma unroll
        for (int l = 0; l < 4; ++l) {
            int idx = tid + l * 256;          // 0..1023
            int r = idx >> 4, c = idx & 15;   // A tile 64x16
            As[c][r] = A[(long)(bm + r) * K + k0 + c];
            int rb = idx >> 6, cb = idx & 63; // B tile 16x64
            Bs[rb][cb] = B[(long)(k0 + rb) * N + bn + cb];
        }
        __syncthreads();
#pragma unroll
        for (int kk = 0; kk < 16; ++kk) {
            float a[4], b[4];
#pragma unroll
            for (int i = 0; i < 4; ++i) a[i] = As[kk][tr + 16 * i];
#pragma unroll
            for (int j = 0; j < 4; ++j) b[j] = Bs[kk][tc + 16 * j];
#pragma unroll
            for (int i = 0; i < 4; ++i)
#pragma unroll
                for (int j = 0; j < 4; ++j) acc[i][j] += a[i] * b[j];
        }
        __syncthreads();
    }
#pragma unroll
    for (int i = 0; i < 4; ++i)
#pragma unroll
        for (int j = 0; j < 4; ++j) {
            int row = bm + tr + 16 * i, col = bn + tc + 16 * j;
            if (KV) {
                // row = b*SEQ+t ; col = h*64+d  ->  ((b*4+h)*SEQ + t)*64 + d
                long oidx = (((long)((row >> 11) * NKV + (col >> 6)) * SEQ + (row & (SEQ - 1))) << 6) | (col & 63);
                C[oidx] = acc[i][j];
            } else {
                C[(long)row * N + col] = acc[i][j];
            }
        }
}

// ---------------------------------------------------------------------------
// RoPE in place, fp32: Q ([ROWS,768], heads 0..11, folds 1/8 scale) and
// K cache ((B,4,SEQ,64), heads 12..15).
// ---------------------------------------------------------------------------
__global__ void rope_f(float* Qp, float* Kc) {
    int tid = blockIdx.x * blockDim.x + threadIdx.x;
    int j = tid & 31;
    int head = (tid >> 5) & 15;
    int row = tid >> 9;           // 0..4095
    int t = row & (SEQ - 1);
    int b = row >> 11;
    float inv = expf(-(float)j * 0.2878231366f);  // ln(10000)/32
    float s, c;
    sincosf((float)t * inv, &s, &c);
    float* p;
    float scale;
    if (head < NHEADS) {
        p = Qp + (long)row * DMODEL + head * DHEAD;
        scale = 0.125f;  // 1/sqrt(64)
    } else {
        p = Kc + (((long)(b * NKV + (head - NHEADS)) * SEQ + t) << 6);
        scale = 1.0f;
    }
    float x1 = p[j], x2 = p[j + 32];
    p[j] = (x1 * c - x2 * s) * scale;
    p[j + 32] = (x2 * c + x1 * s) * scale;
}

// ---------------------------------------------------------------------------
// Attention, fp32, IN PLACE over Q. One wave per (b,h,t); Q pre-scaled 1/8.
// Wave (b,h,t) is the unique reader of q slice [b,t,h*64..]; writes its ATT
// output to that same slice only after consuming q -> no hazard.
// Allowed keys: [0, min(63,t)] U [max(64, t-511), t]  (nj <= 576).
// ---------------------------------------------------------------------------
__global__ void attn_f(float* QA, const float* __restrict__ Kc,
                       const float* __restrict__ Vc) {
    __shared__ float sc[4][MAXJ];
    __shared__ float qs[4][64];
    const int wave = threadIdx.x >> 6;
    const int lane = threadIdx.x & 63;
    const int gid = blockIdx.x * 4 + wave;  // 0..49151
    const int t = gid & (SEQ - 1);
    const int bh = gid >> 11;               // b*12 + h
    const int b = bh / NHEADS, h = bh % NHEADS;
    const int kvh = h / (NHEADS / NKV);
    const int kvrow0 = (b * NKV + kvh) * SEQ;

    const long qidx = (long)(b * SEQ + t) * DMODEL + h * DHEAD + lane;
    qs[wave][lane] = QA[qidx];
    __syncthreads();

    const int n1 = min(GLB, t + 1);
    const int lo2 = max(GLB, t - (WIN - 1));
    const int n2 = (t >= GLB) ? (t - lo2 + 1) : 0;
    const int nj = n1 + n2;

    float mymax = -1e30f;
    for (int idx = lane; idx < nj; idx += 64) {
        int j = (idx < n1) ? idx : (lo2 + idx - n1);
        const float4* kp = (const float4*)(Kc + ((long)(kvrow0 + j) << 6));
        float dot = 0.f;
#pragma unroll
        for (int m = 0; m < 16; ++m) {
            float4 u = kp[m];
            const float* qq = &qs[wave][4 * m];
            dot += qq[0] * u.x + qq[1] * u.y + qq[2] * u.z + qq[3] * u.w;
        }
        sc[wave][idx] = dot;
        mymax = fmaxf(mymax, dot);
    }
#pragma unroll
    for (int off = 32; off >= 1; off >>= 1)
        mymax = fmaxf(mymax, __shfl_xor(mymax, off, 64));

    float lsum = 0.f;
    for (int idx = lane; idx < nj; idx += 64) {
        float e = __expf(sc[wave][idx] - mymax);
        sc[wave][idx] = e;
        lsum += e;
    }
#pragma unroll
    for (int off = 32; off >= 1; off >>= 1) lsum += __shfl_xor(lsum, off, 64);
    __syncthreads();

    float acc = 0.f;
    for (int idx = 0; idx < nj; ++idx) {
        int j = (idx < n1) ? idx : (lo2 + idx - n1);
        acc += sc[wave][idx] * Vc[(((long)(kvrow0 + j)) << 6) + lane];
    }
    QA[qidx] = acc / lsum;  // in-place ATT write
}

// ---------------------------------------------------------------------------
// In-place output projection: AC[4096,768] <- AC @ Bw (wo, fp32 [768,768]).
// Each block owns a disjoint 16-row stripe; stages all 768 cols of its rows
// into LDS (fp32, padded stride 772) BEFORE any store.
// LDS: 16*772*4 + 16*65*4 = 53.5 KB.
// ---------------------------------------------------------------------------
__global__ __launch_bounds__(256) void oproj16(float* AC, const float* __restrict__ Bw) {
    __shared__ float Ar[16][772];
    __shared__ float Bs[16][64 + 1];
    const int tid = threadIdx.x;
    const long bm = (long)blockIdx.x * 16;

    // Stage A: 16 rows x 768 fp32 = 3072 float4 (192 per row), 12/thread.
    const float4* src = (const float4*)(AC + bm * DMODEL);
#pragma unroll
    for (int l = 0; l < 12; ++l) {
        int idx = tid + l * 256;          // 0..3071
        int row = idx / 192, c = idx % 192;
        float4 u = src[idx];              // contiguous global read
        *(float4*)(&Ar[row][c * 4]) = u;  // row base 3088 B -> 16B aligned
    }
    __syncthreads();

    const int tr = tid >> 4, tc = tid & 15;  // row tr, cols tc+16j
    for (int bn = 0; bn < DMODEL; bn += 64) {
        float acc[4] = {};
        for (int k0 = 0; k0 < DMODEL; k0 += 16) {
#pragma unroll
            for (int l = 0; l < 4; ++l) {
                int idx = tid + l * 256;
                Bs[idx >> 6][idx & 63] = Bw[(long)(k0 + (idx >> 6)) * DMODEL + bn + (idx & 63)];
            }
            __syncthreads();
#pragma unroll
            for (int kk = 0; kk < 16; ++kk) {
                float a = Ar[tr][k0 + kk];  // same addr across tc group: broadcast
#pragma unroll
                for (int j = 0; j < 4; ++j) acc[j] += a * Bs[kk][tc + 16 * j];
            }
            __syncthreads();
        }
#pragma unroll
        for (int j = 0; j < 4; ++j)
            AC[(bm + tr) * DMODEL + bn + tc + 16 * j] = acc[j];
    }
}

// ---------------------------------------------------------------------------
extern "C" void kernel_launch(void* const* d_in, const int* in_sizes, int n_in,
                              void* d_out, int out_size, void* d_ws, size_t ws_size,
                              hipStream_t stream) {
    // Inputs fp32, OUTPUTS FP32 (reference returns float32). Zero d_ws use.
    const float* x = (const float*)d_in[0];
    const float* wq = (const float*)d_in[1];
    const float* wk = (const float*)d_in[2];
    const float* wv = (const float*)d_in[3];
    const float* wo = (const float*)d_in[4];
    float* out = (float*)d_out;                               // [4096,768] - Q, then ATT, then out
    float* out_k = out + (long)ROWS * DMODEL;                 // (B,4,SEQ,64)
    float* out_v = out_k + (long)BATCH * NKV * SEQ * DHEAD;   // (B,4,SEQ,64)

    // 1. Q projection -> out0 region
    gemm_f<false><<<dim3(DMODEL / 64, ROWS / 64), 256, 0, stream>>>(x, wq, out, ROWS, DMODEL, DMODEL);
    // 2. K/V projections straight to kv-cache outputs (pre-RoPE)
    gemm_f<true><<<dim3((NKV * DHEAD) / 64, ROWS / 64), 256, 0, stream>>>(x, wk, out_k, ROWS, NKV * DHEAD, DMODEL);
    gemm_f<true><<<dim3((NKV * DHEAD) / 64, ROWS / 64), 256, 0, stream>>>(x, wv, out_v, ROWS, NKV * DHEAD, DMODEL);
    // 3. RoPE in place on Q (with 1/8 scale) and K cache
    rope_f<<<(ROWS * 16 * 32) / 256, 256, 0, stream>>>(out, out_k);
    // 4. Attention, ATT overwrites Q in place
    attn_f<<<(BATCH * NHEADS * SEQ) / 4, 256, 0, stream>>>(out, out_k, out_v);
    // 5. Output projection in place: out <- ATT @ wo
    oproj16<<<ROWS / 16, 256, 0, stream>>>(out, wo);
}

// Round 6
// 466.998 us; speedup vs baseline: 3.5539x; 3.5539x over previous
//
#include <hip/hip_runtime.h>
#include <hip/hip_bf16.h>

#define BATCH 2
#define SEQ 2048
#define DMODEL 768
#define NHEADS 12
#define NKV 4
#define DHEAD 64
#define WIN 512
#define GLB 64
#define ROWS (BATCH * SEQ)  // 4096

typedef short short8 __attribute__((ext_vector_type(8)));
typedef float f32x4 __attribute__((ext_vector_type(4)));

// fp32 -> bf16 bits, round-to-nearest-even (finite inputs only)
__device__ inline short f2bs(float f) {
    unsigned u = __float_as_uint(f);
    return (short)((u + 0x7fffu + ((u >> 16) & 1u)) >> 16);
}

// ---------------------------------------------------------------------------
// 64x64 tiled GEMM, all fp32. C = A[M,K] @ B[K,N].
// KV=false: C[row*N+col].  KV=true: scatter to (B, NKV, SEQ, DHEAD) layout.
// ---------------------------------------------------------------------------
template <bool KV>
__global__ void gemm_f(const float* __restrict__ A, const float* __restrict__ B,
                       float* __restrict__ C, int M, int N, int K) {
    __shared__ float As[16][64 + 1];
    __shared__ float Bs[16][64 + 1];
    const int bm = blockIdx.y * 64, bn = blockIdx.x * 64;
    const int tid = threadIdx.x;
    const int tr = tid >> 4, tc = tid & 15;
    float acc[4][4] = {};
    for (int k0 = 0; k0 < K; k0 += 16) {
#pragma unroll
        for (int l = 0; l < 4; ++l) {
            int idx = tid + l * 256;          // 0..1023
            int r = idx >> 4, c = idx & 15;   // A tile 64x16
            As[c][r] = A[(long)(bm + r) * K + k0 + c];
            int rb = idx >> 6, cb = idx & 63; // B tile 16x64
            Bs[rb][cb] = B[(long)(k0 + rb) * N + bn + cb];
        }
        __syncthreads();
#pragma unroll
        for (int kk = 0; kk < 16; ++kk) {
            float a[4], b[4];
#pragma unroll
            for (int i = 0; i < 4; ++i) a[i] = As[kk][tr + 16 * i];
#pragma unroll
            for (int j = 0; j < 4; ++j) b[j] = Bs[kk][tc + 16 * j];
#pragma unroll
            for (int i = 0; i < 4; ++i)
#pragma unroll
                for (int j = 0; j < 4; ++j) acc[i][j] += a[i] * b[j];
        }
        __syncthreads();
    }
#pragma unroll
    for (int i = 0; i < 4; ++i)
#pragma unroll
        for (int j = 0; j < 4; ++j) {
            int row = bm + tr + 16 * i, col = bn + tc + 16 * j;
            if (KV) {
                long oidx = (((long)((row >> 11) * NKV + (col >> 6)) * SEQ + (row & (SEQ - 1))) << 6) | (col & 63);
                C[oidx] = acc[i][j];
            } else {
                C[(long)row * N + col] = acc[i][j];
            }
        }
}

// ---------------------------------------------------------------------------
// RoPE in place, fp32: Q ([ROWS,768], heads 0..11, folds 1/8 scale) and
// K cache ((B,4,SEQ,64), heads 12..15).
// ---------------------------------------------------------------------------
__global__ void rope_f(float* Qp, float* Kc) {
    int tid = blockIdx.x * blockDim.x + threadIdx.x;
    int j = tid & 31;
    int head = (tid >> 5) & 15;
    int row = tid >> 9;           // 0..4095
    int t = row & (SEQ - 1);
    int b = row >> 11;
    float inv = expf(-(float)j * 0.2878231366f);  // ln(10000)/32
    float s, c;
    sincosf((float)t * inv, &s, &c);
    float* p;
    float scale;
    if (head < NHEADS) {
        p = Qp + (long)row * DMODEL + head * DHEAD;
        scale = 0.125f;  // 1/sqrt(64)
    } else {
        p = Kc + (((long)(b * NKV + (head - NHEADS)) * SEQ + t) << 6);
        scale = 1.0f;
    }
    float x1 = p[j], x2 = p[j + 32];
    p[j] = (x1 * c - x2 * s) * scale;
    p[j + 32] = (x2 * c + x1 * s) * scale;
}

// ---------------------------------------------------------------------------
// Flash attention, bf16 MFMA (16x16x32), fp32 accumulate.
// Block = one (b,h) x 64-row Q tile; wave w owns Q rows [t0+16w, t0+16w+16).
// Key tiles of 32: global tiles (0,32) first -- guarantees every row's running
// max is finite after tile 0 (every row t has key 0 allowed) -- then window
// tiles [max(64,t0-511) & ~31 ... t0+63].
// K is read direct-from-global into B-frags (rows contiguous in K cache).
// V is staged transposed (Vt[d][key], stride 34 -> ~2-way banks on b32).
// P round-trips through per-wave LDS (C-layout -> A-layout, m120 recipe).
// Layouts (verified, guide S3): A[m=lane&15][k=quad*8+i]; B[n=lane&15][k=quad*8+i];
// C/D col=lane&15, row=quad*4+reg.
// ---------------------------------------------------------------------------
#define VSTR 34
#define PSTR 34

__global__ __launch_bounds__(256) void flash_attn(
    const float* __restrict__ Q, const float* __restrict__ Kc,
    const float* __restrict__ Vc, float* __restrict__ ATT) {
    __shared__ short Vt[64 * VSTR];       // V^T tile: Vt[d*VSTR + key]
    __shared__ short Pl[4][16 * PSTR];    // per-wave P: Pl[w][m*PSTR + key]
    const int tid = threadIdx.x;
    const int w = tid >> 6, lane = tid & 63;
    const int m_ = lane & 15, quad = lane >> 4;
    const int t0 = (blockIdx.x & 31) << 6;
    const int bh = blockIdx.x >> 5;       // b*12 + h
    const int b = bh / NHEADS, h = bh % NHEADS;
    const int kvh = h / (NHEADS / NKV);
    const long kvbase = ((long)(b * NKV + kvh) * SEQ) << 6;

    // Q A-frags (2 k-halves), rows t0+16w+m_ (pre-scaled by 1/8 in rope_f)
    short8 qf[2];
    {
        const int qt = t0 + w * 16 + m_;
        const float* qp = Q + (long)(b * SEQ + qt) * DMODEL + h * DHEAD + quad * 8;
        float4 a0 = *(const float4*)(qp);
        float4 a1 = *(const float4*)(qp + 4);
        float4 a2 = *(const float4*)(qp + 32);
        float4 a3 = *(const float4*)(qp + 36);
        short8 v0, v1;
        v0[0] = f2bs(a0.x); v0[1] = f2bs(a0.y); v0[2] = f2bs(a0.z); v0[3] = f2bs(a0.w);
        v0[4] = f2bs(a1.x); v0[5] = f2bs(a1.y); v0[6] = f2bs(a1.z); v0[7] = f2bs(a1.w);
        v1[0] = f2bs(a2.x); v1[1] = f2bs(a2.y); v1[2] = f2bs(a2.z); v1[3] = f2bs(a2.w);
        v1[4] = f2bs(a3.x); v1[5] = f2bs(a3.y); v1[6] = f2bs(a3.z); v1[7] = f2bs(a3.w);
        qf[0] = v0; qf[1] = v1;
    }

    f32x4 of[4];
#pragma unroll
    for (int i = 0; i < 4; ++i) of[i] = (f32x4){0.f, 0.f, 0.f, 0.f};
    float mr[4] = {-1e30f, -1e30f, -1e30f, -1e30f};
    float lr[4] = {0.f, 0.f, 0.f, 0.f};

    int wlo = t0 - (WIN - 1);
    if (wlo < GLB) wlo = GLB;
    wlo &= ~31;
    const int nwin = (t0 + 63 >= wlo) ? (((t0 + 63 - wlo) >> 5) + 1) : 0;
    const int ntile = 2 + nwin;

    for (int tI = 0; tI < ntile; ++tI) {
        const int kb = (tI < 2) ? (tI << 5) : (wlo + ((tI - 2) << 5));
        __syncthreads();  // protect previous Vt from overwrite
        {   // stage V^T (fp32 -> bf16): thread -> key=tid>>3, d-chunk=(tid&7)*8
            const int key = tid >> 3, d0 = (tid & 7) << 3;
            const float* vp = Vc + kvbase + ((long)(kb + key) << 6) + d0;
            float4 u0 = *(const float4*)vp, u1 = *(const float4*)(vp + 4);
            Vt[(d0 + 0) * VSTR + key] = f2bs(u0.x);
            Vt[(d0 + 1) * VSTR + key] = f2bs(u0.y);
            Vt[(d0 + 2) * VSTR + key] = f2bs(u0.z);
            Vt[(d0 + 3) * VSTR + key] = f2bs(u0.w);
            Vt[(d0 + 4) * VSTR + key] = f2bs(u1.x);
            Vt[(d0 + 5) * VSTR + key] = f2bs(u1.y);
            Vt[(d0 + 6) * VSTR + key] = f2bs(u1.z);
            Vt[(d0 + 7) * VSTR + key] = f2bs(u1.w);
        }
        __syncthreads();

        // S = Q K^T : two 16x16 sub-tiles (keys kb+0..15, kb+16..31)
        f32x4 s[2];
#pragma unroll
        for (int st = 0; st < 2; ++st) {
            const float* kp = Kc + kvbase + ((long)(kb + st * 16 + m_) << 6) + quad * 8;
            float4 c0 = *(const float4*)(kp);
            float4 c1 = *(const float4*)(kp + 4);
            float4 c2 = *(const float4*)(kp + 32);
            float4 c3 = *(const float4*)(kp + 36);
            short8 k0, k1;
            k0[0] = f2bs(c0.x); k0[1] = f2bs(c0.y); k0[2] = f2bs(c0.z); k0[3] = f2bs(c0.w);
            k0[4] = f2bs(c1.x); k0[5] = f2bs(c1.y); k0[6] = f2bs(c1.z); k0[7] = f2bs(c1.w);
            k1[0] = f2bs(c2.x); k1[1] = f2bs(c2.y); k1[2] = f2bs(c2.z); k1[3] = f2bs(c2.w);
            k1[4] = f2bs(c3.x); k1[5] = f2bs(c3.y); k1[6] = f2bs(c3.z); k1[7] = f2bs(c3.w);
            f32x4 acc = (f32x4){0.f, 0.f, 0.f, 0.f};
            acc = __builtin_amdgcn_mfma_f32_16x16x32_bf16(qf[0], k0, acc, 0, 0, 0);
            acc = __builtin_amdgcn_mfma_f32_16x16x32_bf16(qf[1], k1, acc, 0, 0, 0);
            s[st] = acc;
        }
        // exact mask: allowed = (j<=t) && (j>t-512 || j<64 || t<64)
        const int trow = t0 + w * 16 + quad * 4;
#pragma unroll
        for (int st = 0; st < 2; ++st) {
            const int key = kb + st * 16 + m_;
#pragma unroll
            for (int r = 0; r < 4; ++r) {
                const int tq = trow + r;
                const bool ok = (key <= tq) && ((key > tq - WIN) || (key < GLB) || (tq < GLB));
                if (!ok) s[st][r] = -1e30f;
            }
        }
        // online softmax (row stats across 16 col-lanes within quad group)
#pragma unroll
        for (int r = 0; r < 4; ++r) {
            float tm = fmaxf(s[0][r], s[1][r]);
            tm = fmaxf(tm, __shfl_xor(tm, 1, 64));
            tm = fmaxf(tm, __shfl_xor(tm, 2, 64));
            tm = fmaxf(tm, __shfl_xor(tm, 4, 64));
            tm = fmaxf(tm, __shfl_xor(tm, 8, 64));
            const float mnew = fmaxf(mr[r], tm);
            const float alpha = __expf(mr[r] - mnew);
            mr[r] = mnew;
            const float p0 = __expf(s[0][r] - mnew);
            const float p1 = __expf(s[1][r] - mnew);
            float rs = p0 + p1;
            rs += __shfl_xor(rs, 1, 64);
            rs += __shfl_xor(rs, 2, 64);
            rs += __shfl_xor(rs, 4, 64);
            rs += __shfl_xor(rs, 8, 64);
            lr[r] = lr[r] * alpha + rs;
#pragma unroll
            for (int dt = 0; dt < 4; ++dt) of[dt][r] *= alpha;
            Pl[w][(quad * 4 + r) * PSTR + m_] = f2bs(p0);
            Pl[w][(quad * 4 + r) * PSTR + 16 + m_] = f2bs(p1);
        }
        // P: C-layout -> A-layout via per-wave LDS (same-wave RAW: DS in-order)
        short8 pf;
        {
            const short* pp = &Pl[w][m_ * PSTR + quad * 8];
#pragma unroll
            for (int i = 0; i < 8; ++i) pf[i] = pp[i];
        }
        // O += P V  (4 d-sub-tiles of 16)
#pragma unroll
        for (int dt = 0; dt < 4; ++dt) {
            const short* vp2 = &Vt[(dt * 16 + m_) * VSTR + quad * 8];
            short8 vf;
#pragma unroll
            for (int i = 0; i < 8; ++i) vf[i] = vp2[i];
            of[dt] = __builtin_amdgcn_mfma_f32_16x16x32_bf16(pf, vf, of[dt], 0, 0, 0);
        }
    }
    // epilogue: O / l, write fp32
#pragma unroll
    for (int r = 0; r < 4; ++r) {
        const int tq = t0 + w * 16 + quad * 4 + r;
        const float inv = 1.0f / lr[r];
        float* op = ATT + (long)(b * SEQ + tq) * DMODEL + h * DHEAD + m_;
        op[0] = of[0][r] * inv;
        op[16] = of[1][r] * inv;
        op[32] = of[2][r] * inv;
        op[48] = of[3][r] * inv;
    }
}

// ---------------------------------------------------------------------------
extern "C" void kernel_launch(void* const* d_in, const int* in_sizes, int n_in,
                              void* d_out, int out_size, void* d_ws, size_t ws_size,
                              hipStream_t stream) {
    const float* x = (const float*)d_in[0];
    const float* wq = (const float*)d_in[1];
    const float* wk = (const float*)d_in[2];
    const float* wv = (const float*)d_in[3];
    const float* wo = (const float*)d_in[4];
    float* out = (float*)d_out;                               // [4096,768]: Q then final out
    float* out_k = out + (long)ROWS * DMODEL;                 // (B,4,SEQ,64)
    float* out_v = out_k + (long)BATCH * NKV * SEQ * DHEAD;   // (B,4,SEQ,64)
    float* ATT = (float*)d_ws;                                // 12 MiB fp32 (proven OK R3/R4)

    // 1. Q projection -> out region (Q's temporary home)
    gemm_f<false><<<dim3(DMODEL / 64, ROWS / 64), 256, 0, stream>>>(x, wq, out, ROWS, DMODEL, DMODEL);
    // 2. K/V projections straight to kv-cache outputs (pre-RoPE)
    gemm_f<true><<<dim3((NKV * DHEAD) / 64, ROWS / 64), 256, 0, stream>>>(x, wk, out_k, ROWS, NKV * DHEAD, DMODEL);
    gemm_f<true><<<dim3((NKV * DHEAD) / 64, ROWS / 64), 256, 0, stream>>>(x, wv, out_v, ROWS, NKV * DHEAD, DMODEL);
    // 3. RoPE in place on Q (with 1/8 scale) and K cache
    rope_f<<<(ROWS * 16 * 32) / 256, 256, 0, stream>>>(out, out_k);
    // 4. Flash attention: Q(out) x KV(out_k/out_v) -> ATT (ws)
    flash_attn<<<(BATCH * NHEADS) * (SEQ / 64), 256, 0, stream>>>(out, out_k, out_v, ATT);
    // 5. Output projection: out <- ATT @ wo
    gemm_f<false><<<dim3(DMODEL / 64, ROWS / 64), 256, 0, stream>>>(ATT, wo, out, ROWS, DMODEL, DMODEL);
}

// Round 7
// 270.154 us; speedup vs baseline: 6.1435x; 1.7286x over previous
//
#include <hip/hip_runtime.h>
#include <hip/hip_bf16.h>

#define BATCH 2
#define SEQ 2048
#define DMODEL 768
#define NHEADS 12
#define NKV 4
#define DHEAD 64
#define WIN 512
#define GLB 64
#define ROWS (BATCH * SEQ)  // 4096

typedef short short8 __attribute__((ext_vector_type(8)));
typedef float f32x4 __attribute__((ext_vector_type(4)));

// fp32 -> bf16 bits, round-to-nearest-even (finite inputs only)
__device__ inline short f2bs(float f) {
    unsigned u = __float_as_uint(f);
    return (short)((u + 0x7fffu + ((u >> 16) & 1u)) >> 16);
}

// ---------------------------------------------------------------------------
// Transpose + bf16-convert: in[K,N] fp32 -> out[N,K] bf16 bits.
// 32x32 tiles, 256 threads.
// ---------------------------------------------------------------------------
__global__ __launch_bounds__(256) void transp(const float* __restrict__ in,
                                              short* __restrict__ out, int K, int N) {
    __shared__ float t[32][33];
    const int k0 = blockIdx.x * 32, n0 = blockIdx.y * 32;
    const int x = threadIdx.x & 31, y = threadIdx.x >> 5;  // y in [0,8)
#pragma unroll
    for (int i = 0; i < 32; i += 8)
        t[y + i][x] = in[(long)(k0 + y + i) * N + n0 + x];
    __syncthreads();
#pragma unroll
    for (int i = 0; i < 32; i += 8)
        out[(long)(n0 + y + i) * K + k0 + x] = f2bs(t[x][y + i]);
}

// ---------------------------------------------------------------------------
// MFMA GEMM (TN): C[M,N] = A[M,K] @ Bt[N,K]^T, fp32 accumulate, fp32 out.
// TA = float (convert to bf16 in staging) or short (raw bf16 bits).
// 128x128 tile, BK=32; 4 waves in 2x2, each 4x4 grid of 16x16x32 MFMA.
// LDS rows stride 40 shorts (80 B): 16-B aligned for ds_read_b128, ~2-way banks.
// Fragment layouts per verified m89/m120 mapping:
//   A[m=lane&15][k=quad*8+i], B[n=lane&15][k=quad*8+i], C/D row=quad*4+reg, col=lane&15.
// KV=true: scatter C to (B, NKV, SEQ, DHEAD) kv-cache layout.
// ---------------------------------------------------------------------------
#define LST 40

template <typename TA, bool KV>
__global__ __launch_bounds__(256) void gemm_tn(const TA* __restrict__ A,
                                               const short* __restrict__ Bt,
                                               float* __restrict__ C,
                                               int M, int N, int K) {
    __shared__ short As_[128 * LST];
    __shared__ short Bs_[128 * LST];
    const int tid = threadIdx.x;
    const int lane = tid & 63, w = tid >> 6;
    const int m_ = lane & 15, quad = lane >> 4;
    const int wm = w >> 1, wn = w & 1;
    const long bm = (long)blockIdx.y * 128, bn = (long)blockIdx.x * 128;
    const int sr = tid >> 1, sh = (tid & 1) * 16;  // staging: row, k-half

    f32x4 acc[4][4];
#pragma unroll
    for (int i = 0; i < 4; ++i)
#pragma unroll
        for (int j = 0; j < 4; ++j) acc[i][j] = (f32x4){0.f, 0.f, 0.f, 0.f};

    for (int k0 = 0; k0 < K; k0 += 32) {
        short av[16], bv[16];
        if (sizeof(TA) == 4) {  // fp32 A: load 16 floats, convert
            const float* ap = (const float*)A + (bm + sr) * K + k0 + sh;
            float ff[16];
#pragma unroll
            for (int i = 0; i < 4; ++i) *(float4*)&ff[4 * i] = ((const float4*)ap)[i];
#pragma unroll
            for (int i = 0; i < 16; ++i) av[i] = f2bs(ff[i]);
        } else {                // bf16 A: straight copy
            const short* ap = (const short*)A + (bm + sr) * K + k0 + sh;
            *(uint4*)&av[0] = ((const uint4*)ap)[0];
            *(uint4*)&av[8] = ((const uint4*)ap)[1];
        }
        {
            const short* bp = Bt + (bn + sr) * K + k0 + sh;
            *(uint4*)&bv[0] = ((const uint4*)bp)[0];
            *(uint4*)&bv[8] = ((const uint4*)bp)[1];
        }
        __syncthreads();  // previous iteration's frag reads complete
        short* ad = &As_[sr * LST + sh];
        short* bd = &Bs_[sr * LST + sh];
#pragma unroll
        for (int i = 0; i < 4; ++i) {
            ((uint2*)ad)[i] = ((uint2*)av)[i];
            ((uint2*)bd)[i] = ((uint2*)bv)[i];
        }
        __syncthreads();

        short8 af[4], bf[4];
#pragma unroll
        for (int i = 0; i < 4; ++i)
            af[i] = *(const short8*)&As_[(wm * 64 + i * 16 + m_) * LST + quad * 8];
#pragma unroll
        for (int j = 0; j < 4; ++j)
            bf[j] = *(const short8*)&Bs_[(wn * 64 + j * 16 + m_) * LST + quad * 8];
#pragma unroll
        for (int i = 0; i < 4; ++i)
#pragma unroll
            for (int j = 0; j < 4; ++j)
                acc[i][j] = __builtin_amdgcn_mfma_f32_16x16x32_bf16(af[i], bf[j], acc[i][j], 0, 0, 0);
    }

#pragma unroll
    for (int i = 0; i < 4; ++i) {
        const int row0 = (int)bm + wm * 64 + i * 16 + quad * 4;
#pragma unroll
        for (int j = 0; j < 4; ++j) {
            const int col = (int)bn + wn * 64 + j * 16 + m_;
#pragma unroll
            for (int r = 0; r < 4; ++r) {
                const int rw = row0 + r;
                if (KV) {
                    long oidx = (((long)((rw >> 11) * NKV + (col >> 6)) * SEQ + (rw & (SEQ - 1))) << 6) | (col & 63);
                    C[oidx] = acc[i][j][r];
                } else {
                    C[(long)rw * N + col] = acc[i][j][r];
                }
            }
        }
    }
}

// ---------------------------------------------------------------------------
// RoPE in place, fp32: Q ([ROWS,768], heads 0..11, folds 1/8 scale) and
// K cache ((B,4,SEQ,64), heads 12..15).
// ---------------------------------------------------------------------------
__global__ void rope_f(float* Qp, float* Kc) {
    int tid = blockIdx.x * blockDim.x + threadIdx.x;
    int j = tid & 31;
    int head = (tid >> 5) & 15;
    int row = tid >> 9;           // 0..4095
    int t = row & (SEQ - 1);
    int b = row >> 11;
    float inv = expf(-(float)j * 0.2878231366f);  // ln(10000)/32
    float s, c;
    sincosf((float)t * inv, &s, &c);
    float* p;
    float scale;
    if (head < NHEADS) {
        p = Qp + (long)row * DMODEL + head * DHEAD;
        scale = 0.125f;  // 1/sqrt(64)
    } else {
        p = Kc + (((long)(b * NKV + (head - NHEADS)) * SEQ + t) << 6);
        scale = 1.0f;
    }
    float x1 = p[j], x2 = p[j + 32];
    p[j] = (x1 * c - x2 * s) * scale;
    p[j + 32] = (x2 * c + x1 * s) * scale;
}

// ---------------------------------------------------------------------------
// Flash attention, bf16 MFMA (16x16x32), fp32 accumulate, bf16 ATT out.
// Block = one (b,h) x 64-row Q tile; wave w owns Q rows [t0+16w, t0+16w+16).
// Global key tiles (0,32) first (finite running max for every row), then
// window tiles. K direct-from-global into B-frags; V staged transposed in LDS;
// P via per-wave LDS round-trip (C-layout -> A-layout).
// ---------------------------------------------------------------------------
#define VSTR 34
#define PSTR 34

__global__ __launch_bounds__(256) void flash_attn(
    const float* __restrict__ Q, const float* __restrict__ Kc,
    const float* __restrict__ Vc, short* __restrict__ ATT) {
    __shared__ short Vt[64 * VSTR];       // V^T tile: Vt[d*VSTR + key]
    __shared__ short Pl[4][16 * PSTR];    // per-wave P: Pl[w][m*PSTR + key]
    const int tid = threadIdx.x;
    const int w = tid >> 6, lane = tid & 63;
    const int m_ = lane & 15, quad = lane >> 4;
    const int t0 = (blockIdx.x & 31) << 6;
    const int bh = blockIdx.x >> 5;       // b*12 + h
    const int b = bh / NHEADS, h = bh % NHEADS;
    const int kvh = h / (NHEADS / NKV);
    const long kvbase = ((long)(b * NKV + kvh) * SEQ) << 6;

    short8 qf[2];
    {
        const int qt = t0 + w * 16 + m_;
        const float* qp = Q + (long)(b * SEQ + qt) * DMODEL + h * DHEAD + quad * 8;
        float4 a0 = *(const float4*)(qp);
        float4 a1 = *(const float4*)(qp + 4);
        float4 a2 = *(const float4*)(qp + 32);
        float4 a3 = *(const float4*)(qp + 36);
        short8 v0, v1;
        v0[0] = f2bs(a0.x); v0[1] = f2bs(a0.y); v0[2] = f2bs(a0.z); v0[3] = f2bs(a0.w);
        v0[4] = f2bs(a1.x); v0[5] = f2bs(a1.y); v0[6] = f2bs(a1.z); v0[7] = f2bs(a1.w);
        v1[0] = f2bs(a2.x); v1[1] = f2bs(a2.y); v1[2] = f2bs(a2.z); v1[3] = f2bs(a2.w);
        v1[4] = f2bs(a3.x); v1[5] = f2bs(a3.y); v1[6] = f2bs(a3.z); v1[7] = f2bs(a3.w);
        qf[0] = v0; qf[1] = v1;
    }

    f32x4 of[4];
#pragma unroll
    for (int i = 0; i < 4; ++i) of[i] = (f32x4){0.f, 0.f, 0.f, 0.f};
    float mr[4] = {-1e30f, -1e30f, -1e30f, -1e30f};
    float lr[4] = {0.f, 0.f, 0.f, 0.f};

    int wlo = t0 - (WIN - 1);
    if (wlo < GLB) wlo = GLB;
    wlo &= ~31;
    const int nwin = (t0 + 63 >= wlo) ? (((t0 + 63 - wlo) >> 5) + 1) : 0;
    const int ntile = 2 + nwin;

    for (int tI = 0; tI < ntile; ++tI) {
        const int kb = (tI < 2) ? (tI << 5) : (wlo + ((tI - 2) << 5));
        __syncthreads();
        {
            const int key = tid >> 3, d0 = (tid & 7) << 3;
            const float* vp = Vc + kvbase + ((long)(kb + key) << 6) + d0;
            float4 u0 = *(const float4*)vp, u1 = *(const float4*)(vp + 4);
            Vt[(d0 + 0) * VSTR + key] = f2bs(u0.x);
            Vt[(d0 + 1) * VSTR + key] = f2bs(u0.y);
            Vt[(d0 + 2) * VSTR + key] = f2bs(u0.z);
            Vt[(d0 + 3) * VSTR + key] = f2bs(u0.w);
            Vt[(d0 + 4) * VSTR + key] = f2bs(u1.x);
            Vt[(d0 + 5) * VSTR + key] = f2bs(u1.y);
            Vt[(d0 + 6) * VSTR + key] = f2bs(u1.z);
            Vt[(d0 + 7) * VSTR + key] = f2bs(u1.w);
        }
        __syncthreads();

        f32x4 s[2];
#pragma unroll
        for (int st = 0; st < 2; ++st) {
            const float* kp = Kc + kvbase + ((long)(kb + st * 16 + m_) << 6) + quad * 8;
            float4 c0 = *(const float4*)(kp);
            float4 c1 = *(const float4*)(kp + 4);
            float4 c2 = *(const float4*)(kp + 32);
            float4 c3 = *(const float4*)(kp + 36);
            short8 k0, k1;
            k0[0] = f2bs(c0.x); k0[1] = f2bs(c0.y); k0[2] = f2bs(c0.z); k0[3] = f2bs(c0.w);
            k0[4] = f2bs(c1.x); k0[5] = f2bs(c1.y); k0[6] = f2bs(c1.z); k0[7] = f2bs(c1.w);
            k1[0] = f2bs(c2.x); k1[1] = f2bs(c2.y); k1[2] = f2bs(c2.z); k1[3] = f2bs(c2.w);
            k1[4] = f2bs(c3.x); k1[5] = f2bs(c3.y); k1[6] = f2bs(c3.z); k1[7] = f2bs(c3.w);
            f32x4 acc = (f32x4){0.f, 0.f, 0.f, 0.f};
            acc = __builtin_amdgcn_mfma_f32_16x16x32_bf16(qf[0], k0, acc, 0, 0, 0);
            acc = __builtin_amdgcn_mfma_f32_16x16x32_bf16(qf[1], k1, acc, 0, 0, 0);
            s[st] = acc;
        }
        const int trow = t0 + w * 16 + quad * 4;
#pragma unroll
        for (int st = 0; st < 2; ++st) {
            const int key = kb + st * 16 + m_;
#pragma unroll
            for (int r = 0; r < 4; ++r) {
                const int tq = trow + r;
                const bool ok = (key <= tq) && ((key > tq - WIN) || (key < GLB) || (tq < GLB));
                if (!ok) s[st][r] = -1e30f;
            }
        }
#pragma unroll
        for (int r = 0; r < 4; ++r) {
            float tm = fmaxf(s[0][r], s[1][r]);
            tm = fmaxf(tm, __shfl_xor(tm, 1, 64));
            tm = fmaxf(tm, __shfl_xor(tm, 2, 64));
            tm = fmaxf(tm, __shfl_xor(tm, 4, 64));
            tm = fmaxf(tm, __shfl_xor(tm, 8, 64));
            const float mnew = fmaxf(mr[r], tm);
            const float alpha = __expf(mr[r] - mnew);
            mr[r] = mnew;
            const float p0 = __expf(s[0][r] - mnew);
            const float p1 = __expf(s[1][r] - mnew);
            float rs = p0 + p1;
            rs += __shfl_xor(rs, 1, 64);
            rs += __shfl_xor(rs, 2, 64);
            rs += __shfl_xor(rs, 4, 64);
            rs += __shfl_xor(rs, 8, 64);
            lr[r] = lr[r] * alpha + rs;
#pragma unroll
            for (int dt = 0; dt < 4; ++dt) of[dt][r] *= alpha;
            Pl[w][(quad * 4 + r) * PSTR + m_] = f2bs(p0);
            Pl[w][(quad * 4 + r) * PSTR + 16 + m_] = f2bs(p1);
        }
        short8 pf;
        {
            const short* pp = &Pl[w][m_ * PSTR + quad * 8];
#pragma unroll
            for (int i = 0; i < 8; ++i) pf[i] = pp[i];
        }
#pragma unroll
        for (int dt = 0; dt < 4; ++dt) {
            const short* vp2 = &Vt[(dt * 16 + m_) * VSTR + quad * 8];
            short8 vf;
#pragma unroll
            for (int i = 0; i < 8; ++i) vf[i] = vp2[i];
            of[dt] = __builtin_amdgcn_mfma_f32_16x16x32_bf16(pf, vf, of[dt], 0, 0, 0);
        }
    }
#pragma unroll
    for (int r = 0; r < 4; ++r) {
        const int tq = t0 + w * 16 + quad * 4 + r;
        const float inv = 1.0f / lr[r];
        short* op = ATT + (long)(b * SEQ + tq) * DMODEL + h * DHEAD + m_;
        op[0] = f2bs(of[0][r] * inv);
        op[16] = f2bs(of[1][r] * inv);
        op[32] = f2bs(of[2][r] * inv);
        op[48] = f2bs(of[3][r] * inv);
    }
}

// ---------------------------------------------------------------------------
extern "C" void kernel_launch(void* const* d_in, const int* in_sizes, int n_in,
                              void* d_out, int out_size, void* d_ws, size_t ws_size,
                              hipStream_t stream) {
    const float* x = (const float*)d_in[0];
    const float* wq = (const float*)d_in[1];
    const float* wk = (const float*)d_in[2];
    const float* wv = (const float*)d_in[3];
    const float* wo = (const float*)d_in[4];
    float* out = (float*)d_out;                               // [4096,768]: Q then final out
    float* out_k = out + (long)ROWS * DMODEL;                 // (B,4,SEQ,64) fp32
    float* out_v = out_k + (long)BATCH * NKV * SEQ * DHEAD;   // (B,4,SEQ,64) fp32

    // ws layout (shorts): ATTb 3145728 | wqT 589824 | wkT 196608 | wvT 196608 | woT 589824
    // total 9.0 MiB (<= proven-good 12 MiB)
    short* ATTb = (short*)d_ws;
    short* wqT = ATTb + (long)ROWS * DMODEL;
    short* wkT = wqT + DMODEL * DMODEL;
    short* wvT = wkT + DMODEL * (NKV * DHEAD);
    short* woT = wvT + DMODEL * (NKV * DHEAD);

    // 0. Transpose + bf16-convert weights: w[K,N] -> wT[N,K]
    transp<<<dim3(DMODEL / 32, DMODEL / 32), 256, 0, stream>>>(wq, wqT, DMODEL, DMODEL);
    transp<<<dim3(DMODEL / 32, (NKV * DHEAD) / 32), 256, 0, stream>>>(wk, wkT, DMODEL, NKV * DHEAD);
    transp<<<dim3(DMODEL / 32, (NKV * DHEAD) / 32), 256, 0, stream>>>(wv, wvT, DMODEL, NKV * DHEAD);
    transp<<<dim3(DMODEL / 32, DMODEL / 32), 256, 0, stream>>>(wo, woT, DMODEL, DMODEL);

    // 1. Q projection -> out region (fp32)
    gemm_tn<float, false><<<dim3(DMODEL / 128, ROWS / 128), 256, 0, stream>>>(x, wqT, out, ROWS, DMODEL, DMODEL);
    // 2. K/V projections -> kv-cache outputs (fp32, pre-RoPE)
    gemm_tn<float, true><<<dim3((NKV * DHEAD) / 128, ROWS / 128), 256, 0, stream>>>(x, wkT, out_k, ROWS, NKV * DHEAD, DMODEL);
    gemm_tn<float, true><<<dim3((NKV * DHEAD) / 128, ROWS / 128), 256, 0, stream>>>(x, wvT, out_v, ROWS, NKV * DHEAD, DMODEL);
    // 3. RoPE in place on Q (with 1/8 scale) and K cache
    rope_f<<<(ROWS * 16 * 32) / 256, 256, 0, stream>>>(out, out_k);
    // 4. Flash attention -> ATTb (bf16)
    flash_attn<<<(BATCH * NHEADS) * (SEQ / 64), 256, 0, stream>>>(out, out_k, out_v, ATTb);
    // 5. Output projection: out <- ATTb @ woT^T
    gemm_tn<short, false><<<dim3(DMODEL / 128, ROWS / 128), 256, 0, stream>>>(ATTb, woT, out, ROWS, DMODEL, DMODEL);
}

// Round 8
// 228.469 us; speedup vs baseline: 7.2644x; 1.1825x over previous
//
#include <hip/hip_runtime.h>
#include <hip/hip_bf16.h>

#define BATCH 2
#define SEQ 2048
#define DMODEL 768
#define NHEADS 12
#define NKV 4
#define DHEAD 64
#define WIN 512
#define GLB 64
#define ROWS (BATCH * SEQ)  // 4096

typedef short short8 __attribute__((ext_vector_type(8)));
typedef float f32x4 __attribute__((ext_vector_type(4)));

// fp32 -> bf16 bits, round-to-nearest-even (finite inputs only)
__device__ inline short f2bs(float f) {
    unsigned u = __float_as_uint(f);
    return (short)((u + 0x7fffu + ((u >> 16) & 1u)) >> 16);
}

// ---------------------------------------------------------------------------
// Transpose + bf16-convert: in[K,N] fp32 -> out[N,K] bf16 bits. 32x32 tiles.
// ---------------------------------------------------------------------------
__global__ __launch_bounds__(256) void transp(const float* __restrict__ in,
                                              short* __restrict__ out, int K, int N) {
    __shared__ float t[32][33];
    const int k0 = blockIdx.x * 32, n0 = blockIdx.y * 32;
    const int x = threadIdx.x & 31, y = threadIdx.x >> 5;  // y in [0,8)
#pragma unroll
    for (int i = 0; i < 32; i += 8)
        t[y + i][x] = in[(long)(k0 + y + i) * N + n0 + x];
    __syncthreads();
#pragma unroll
    for (int i = 0; i < 32; i += 8)
        out[(long)(n0 + y + i) * K + k0 + x] = f2bs(t[x][y + i]);
}

// ---------------------------------------------------------------------------
// V^T prep: out_v (B,NKV,SEQ,64) fp32 -> Vt (B,NKV,64,SEQ) bf16.
// ---------------------------------------------------------------------------
__global__ __launch_bounds__(256) void vtransp(const float* __restrict__ in,
                                               short* __restrict__ out) {
    __shared__ float t[32][33];
    const long bkv = blockIdx.z;
    const float* ip = in + bkv * SEQ * DHEAD;
    short* op = out + bkv * DHEAD * SEQ;
    const int t0 = blockIdx.x * 32, d0 = blockIdx.y * 32;
    const int x = threadIdx.x & 31, y = threadIdx.x >> 5;
#pragma unroll
    for (int i = 0; i < 32; i += 8)
        t[y + i][x] = ip[(long)(t0 + y + i) * DHEAD + d0 + x];
    __syncthreads();
#pragma unroll
    for (int i = 0; i < 32; i += 8)
        op[(long)(d0 + y + i) * SEQ + t0 + x] = f2bs(t[x][y + i]);
}

// ---------------------------------------------------------------------------
// MFMA GEMM (TN): C = A[M,K] @ Bt[N,K]^T, fp32 accumulate.
// TA = float (bf16-convert in staging) or short (raw bf16 bits).
// MODE 0: plain fp32 C.  MODE 1: 3-way split store (cols 0..767 -> Q fp32
// row-major; 768..1023 -> K cache; 1024..1279 -> V cache, (B,NKV,SEQ,64)).
// MODE 2: plain fp32 C (same as 0; A bf16) -- kept via TA template.
// 128x128 tile, BK=32; 4 waves 2x2, each 4x4 of 16x16x32 MFMA.
// LDS row stride 40 shorts (80 B): 16B-aligned b128 reads, ~2-way banks.
// ---------------------------------------------------------------------------
#define LST 40

template <typename TA, int MODE>
__global__ __launch_bounds__(256) void gemm_tn(const TA* __restrict__ A,
                                               const short* __restrict__ Bt,
                                               float* __restrict__ Cq,
                                               float* __restrict__ Ck,
                                               float* __restrict__ Cv,
                                               int M, int N, int K) {
    __shared__ short As_[128 * LST];
    __shared__ short Bs_[128 * LST];
    const int tid = threadIdx.x;
    const int lane = tid & 63, w = tid >> 6;
    const int m_ = lane & 15, quad = lane >> 4;
    const int wm = w >> 1, wn = w & 1;
    const long bm = (long)blockIdx.y * 128, bn = (long)blockIdx.x * 128;
    const int sr = tid >> 1, sh = (tid & 1) * 16;  // staging: row, k-half

    f32x4 acc[4][4];
#pragma unroll
    for (int i = 0; i < 4; ++i)
#pragma unroll
        for (int j = 0; j < 4; ++j) acc[i][j] = (f32x4){0.f, 0.f, 0.f, 0.f};

    for (int k0 = 0; k0 < K; k0 += 32) {
        short av[16], bv[16];
        if (sizeof(TA) == 4) {
            const float* ap = (const float*)A + (bm + sr) * K + k0 + sh;
            float ff[16];
#pragma unroll
            for (int i = 0; i < 4; ++i) *(float4*)&ff[4 * i] = ((const float4*)ap)[i];
#pragma unroll
            for (int i = 0; i < 16; ++i) av[i] = f2bs(ff[i]);
        } else {
            const short* ap = (const short*)A + (bm + sr) * K + k0 + sh;
            *(uint4*)&av[0] = ((const uint4*)ap)[0];
            *(uint4*)&av[8] = ((const uint4*)ap)[1];
        }
        {
            const short* bp = Bt + (bn + sr) * K + k0 + sh;
            *(uint4*)&bv[0] = ((const uint4*)bp)[0];
            *(uint4*)&bv[8] = ((const uint4*)bp)[1];
        }
        __syncthreads();
        short* ad = &As_[sr * LST + sh];
        short* bd = &Bs_[sr * LST + sh];
#pragma unroll
        for (int i = 0; i < 4; ++i) {
            ((uint2*)ad)[i] = ((uint2*)av)[i];
            ((uint2*)bd)[i] = ((uint2*)bv)[i];
        }
        __syncthreads();

        short8 af[4], bf[4];
#pragma unroll
        for (int i = 0; i < 4; ++i)
            af[i] = *(const short8*)&As_[(wm * 64 + i * 16 + m_) * LST + quad * 8];
#pragma unroll
        for (int j = 0; j < 4; ++j)
            bf[j] = *(const short8*)&Bs_[(wn * 64 + j * 16 + m_) * LST + quad * 8];
#pragma unroll
        for (int i = 0; i < 4; ++i)
#pragma unroll
            for (int j = 0; j < 4; ++j)
                acc[i][j] = __builtin_amdgcn_mfma_f32_16x16x32_bf16(af[i], bf[j], acc[i][j], 0, 0, 0);
    }

#pragma unroll
    for (int i = 0; i < 4; ++i) {
        const int row0 = (int)bm + wm * 64 + i * 16 + quad * 4;
#pragma unroll
        for (int j = 0; j < 4; ++j) {
            const int col = (int)bn + wn * 64 + j * 16 + m_;
#pragma unroll
            for (int r = 0; r < 4; ++r) {
                const int rw = row0 + r;
                const float val = acc[i][j][r];
                if (MODE == 1) {
                    if (col < DMODEL) {
                        Cq[(long)rw * DMODEL + col] = val;
                    } else {
                        const int c2 = col - DMODEL;        // 0..511
                        const int hh = (c2 >> 6) & 3, d = c2 & 63;
                        long oidx = (((long)((rw >> 11) * NKV + hh) * SEQ + (rw & (SEQ - 1))) << 6) | d;
                        ((c2 >> 8) ? Cv : Ck)[oidx] = val;
                    }
                } else {
                    Cq[(long)rw * N + col] = val;
                }
            }
        }
    }
}

// ---------------------------------------------------------------------------
// RoPE in place, fp32: Q ([ROWS,768], heads 0..11, folds 1/8 scale) and
// K cache ((B,4,SEQ,64), heads 12..15).
// ---------------------------------------------------------------------------
__global__ void rope_f(float* Qp, float* Kc) {
    int tid = blockIdx.x * blockDim.x + threadIdx.x;
    int j = tid & 31;
    int head = (tid >> 5) & 15;
    int row = tid >> 9;           // 0..4095
    int t = row & (SEQ - 1);
    int b = row >> 11;
    float inv = expf(-(float)j * 0.2878231366f);  // ln(10000)/32
    float s, c;
    sincosf((float)t * inv, &s, &c);
    float* p;
    float scale;
    if (head < NHEADS) {
        p = Qp + (long)row * DMODEL + head * DHEAD;
        scale = 0.125f;  // 1/sqrt(64)
    } else {
        p = Kc + (((long)(b * NKV + (head - NHEADS)) * SEQ + t) << 6);
        scale = 1.0f;
    }
    float x1 = p[j], x2 = p[j + 32];
    p[j] = (x1 * c - x2 * s) * scale;
    p[j + 32] = (x2 * c + x1 * s) * scale;
}

// ---------------------------------------------------------------------------
// Flash attention v2: no block-level LDS, no __syncthreads. One wave = 16 Q
// rows; 4 waves/block cover a 64-row Q tile of one (b,h).
// K frags: fp32 global + convert. V frags: DIRECT global bf16 loads from
// pre-transposed Vt (B,NKV,64,SEQ). P round-trip via per-wave LDS (validated
// R6/R7). Global key tiles (0,32) first -> finite running max for every row.
// Interior tiles skip the mask (wave-uniform test).
// ---------------------------------------------------------------------------
#define PSTR 34

__global__ __launch_bounds__(256) void flash2(
    const float* __restrict__ Q, const float* __restrict__ Kc,
    const short* __restrict__ Vt, short* __restrict__ ATT) {
    __shared__ short Pl[4][16 * PSTR];
    const int tid = threadIdx.x;
    const int w = tid >> 6, lane = tid & 63;
    const int m_ = lane & 15, quad = lane >> 4;
    const int t0 = (blockIdx.x & 31) << 6;
    const int bh = blockIdx.x >> 5;       // b*12 + h
    const int b = bh / NHEADS, h = bh % NHEADS;
    const int kvh = h / (NHEADS / NKV);
    const long kvbase = ((long)(b * NKV + kvh) * SEQ) << 6;   // fp32 K cache
    const long vtbase = (long)(b * NKV + kvh) * DHEAD * SEQ;  // bf16 V^T

    short8 qf[2];
    {
        const int qt = t0 + w * 16 + m_;
        const float* qp = Q + (long)(b * SEQ + qt) * DMODEL + h * DHEAD + quad * 8;
        float4 a0 = *(const float4*)(qp);
        float4 a1 = *(const float4*)(qp + 4);
        float4 a2 = *(const float4*)(qp + 32);
        float4 a3 = *(const float4*)(qp + 36);
        short8 v0, v1;
        v0[0] = f2bs(a0.x); v0[1] = f2bs(a0.y); v0[2] = f2bs(a0.z); v0[3] = f2bs(a0.w);
        v0[4] = f2bs(a1.x); v0[5] = f2bs(a1.y); v0[6] = f2bs(a1.z); v0[7] = f2bs(a1.w);
        v1[0] = f2bs(a2.x); v1[1] = f2bs(a2.y); v1[2] = f2bs(a2.z); v1[3] = f2bs(a2.w);
        v1[4] = f2bs(a3.x); v1[5] = f2bs(a3.y); v1[6] = f2bs(a3.z); v1[7] = f2bs(a3.w);
        qf[0] = v0; qf[1] = v1;
    }

    f32x4 of[4];
#pragma unroll
    for (int i = 0; i < 4; ++i) of[i] = (f32x4){0.f, 0.f, 0.f, 0.f};
    float mr[4] = {-1e30f, -1e30f, -1e30f, -1e30f};
    float lr[4] = {0.f, 0.f, 0.f, 0.f};

    int wlo = t0 - (WIN - 1);
    if (wlo < GLB) wlo = GLB;
    wlo &= ~31;
    const int nwin = (t0 + 63 >= wlo) ? (((t0 + 63 - wlo) >> 5) + 1) : 0;
    const int ntile = 2 + nwin;
    const int trw = t0 + w * 16;  // wave's first Q row

    for (int tI = 0; tI < ntile; ++tI) {
        const int kb = (tI < 2) ? (tI << 5) : (wlo + ((tI - 2) << 5));

        // S = Q K^T (keys kb..kb+31), K fp32 -> bf16 in registers
        f32x4 s[2];
#pragma unroll
        for (int st = 0; st < 2; ++st) {
            const float* kp = Kc + kvbase + ((long)(kb + st * 16 + m_) << 6) + quad * 8;
            float4 c0 = *(const float4*)(kp);
            float4 c1 = *(const float4*)(kp + 4);
            float4 c2 = *(const float4*)(kp + 32);
            float4 c3 = *(const float4*)(kp + 36);
            short8 k0, k1;
            k0[0] = f2bs(c0.x); k0[1] = f2bs(c0.y); k0[2] = f2bs(c0.z); k0[3] = f2bs(c0.w);
            k0[4] = f2bs(c1.x); k0[5] = f2bs(c1.y); k0[6] = f2bs(c1.z); k0[7] = f2bs(c1.w);
            k1[0] = f2bs(c2.x); k1[1] = f2bs(c2.y); k1[2] = f2bs(c2.z); k1[3] = f2bs(c2.w);
            k1[4] = f2bs(c3.x); k1[5] = f2bs(c3.y); k1[6] = f2bs(c3.z); k1[7] = f2bs(c3.w);
            f32x4 a = (f32x4){0.f, 0.f, 0.f, 0.f};
            a = __builtin_amdgcn_mfma_f32_16x16x32_bf16(qf[0], k0, a, 0, 0, 0);
            a = __builtin_amdgcn_mfma_f32_16x16x32_bf16(qf[1], k1, a, 0, 0, 0);
            s[st] = a;
        }

        // mask unless tile fully allowed for this wave's 16 rows
        const bool fully = (kb + 31 <= trw) &&
                           ((kb >= trw + 16 - WIN) || (kb + 31 < GLB) || (trw + 15 < GLB));
        if (!fully) {
#pragma unroll
            for (int st = 0; st < 2; ++st) {
                const int key = kb + st * 16 + m_;
#pragma unroll
                for (int r = 0; r < 4; ++r) {
                    const int tq = trw + quad * 4 + r;
                    const bool ok = (key <= tq) && ((key > tq - WIN) || (key < GLB) || (tq < GLB));
                    if (!ok) s[st][r] = -1e30f;
                }
            }
        }

        // online softmax
#pragma unroll
        for (int r = 0; r < 4; ++r) {
            float tm = fmaxf(s[0][r], s[1][r]);
            tm = fmaxf(tm, __shfl_xor(tm, 1, 64));
            tm = fmaxf(tm, __shfl_xor(tm, 2, 64));
            tm = fmaxf(tm, __shfl_xor(tm, 4, 64));
            tm = fmaxf(tm, __shfl_xor(tm, 8, 64));
            const float mnew = fmaxf(mr[r], tm);
            const float alpha = __expf(mr[r] - mnew);
            mr[r] = mnew;
            const float p0 = __expf(s[0][r] - mnew);
            const float p1 = __expf(s[1][r] - mnew);
            float rs = p0 + p1;
            rs += __shfl_xor(rs, 1, 64);
            rs += __shfl_xor(rs, 2, 64);
            rs += __shfl_xor(rs, 4, 64);
            rs += __shfl_xor(rs, 8, 64);
            lr[r] = lr[r] * alpha + rs;
#pragma unroll
            for (int dt = 0; dt < 4; ++dt) of[dt][r] *= alpha;
            Pl[w][(quad * 4 + r) * PSTR + m_] = f2bs(p0);
            Pl[w][(quad * 4 + r) * PSTR + 16 + m_] = f2bs(p1);
        }
        // P: C-layout -> A-layout via per-wave LDS (same-wave DS ordering)
        short8 pf;
        {
            const short* pp = &Pl[w][m_ * PSTR + quad * 8];
#pragma unroll
            for (int i = 0; i < 8; ++i) pf[i] = pp[i];
        }
        // O += P V : V^T frags direct from global bf16
#pragma unroll
        for (int dt = 0; dt < 4; ++dt) {
            const short8 vf = *(const short8*)(Vt + vtbase + (long)(dt * 16 + m_) * SEQ + kb + quad * 8);
            of[dt] = __builtin_amdgcn_mfma_f32_16x16x32_bf16(pf, vf, of[dt], 0, 0, 0);
        }
    }

#pragma unroll
    for (int r = 0; r < 4; ++r) {
        const int tq = trw + quad * 4 + r;
        const float inv = 1.0f / lr[r];
        short* op = ATT + (long)(b * SEQ + tq) * DMODEL + h * DHEAD + m_;
        op[0] = f2bs(of[0][r] * inv);
        op[16] = f2bs(of[1][r] * inv);
        op[32] = f2bs(of[2][r] * inv);
        op[48] = f2bs(of[3][r] * inv);
    }
}

// ---------------------------------------------------------------------------
extern "C" void kernel_launch(void* const* d_in, const int* in_sizes, int n_in,
                              void* d_out, int out_size, void* d_ws, size_t ws_size,
                              hipStream_t stream) {
    const float* x = (const float*)d_in[0];
    const float* wq = (const float*)d_in[1];
    const float* wk = (const float*)d_in[2];
    const float* wv = (const float*)d_in[3];
    const float* wo = (const float*)d_in[4];
    float* out = (float*)d_out;                               // [4096,768]: Q home, then final out
    float* out_k = out + (long)ROWS * DMODEL;                 // (B,4,SEQ,64) fp32
    float* out_v = out_k + (long)BATCH * NKV * SEQ * DHEAD;   // (B,4,SEQ,64) fp32

    // ws (shorts): ATTb 3145728 | wqkvT 1280*768 | woT 768*768 | Vt 8*64*2048
    // = 11.0 MiB total (<= proven 12 MiB)
    short* ATTb = (short*)d_ws;
    short* wqkvT = ATTb + (long)ROWS * DMODEL;
    short* woT = wqkvT + (long)(DMODEL + 2 * NKV * DHEAD) * DMODEL;
    short* VtB = woT + (long)DMODEL * DMODEL;

    // 0. Transpose + bf16 weights: wq/wk/wv stacked -> wqkvT [1280][768]; woT
    transp<<<dim3(DMODEL / 32, DMODEL / 32), 256, 0, stream>>>(wq, wqkvT, DMODEL, DMODEL);
    transp<<<dim3(DMODEL / 32, (NKV * DHEAD) / 32), 256, 0, stream>>>(wk, wqkvT + (long)DMODEL * DMODEL, DMODEL, NKV * DHEAD);
    transp<<<dim3(DMODEL / 32, (NKV * DHEAD) / 32), 256, 0, stream>>>(wv, wqkvT + (long)(DMODEL + NKV * DHEAD) * DMODEL, DMODEL, NKV * DHEAD);
    transp<<<dim3(DMODEL / 32, DMODEL / 32), 256, 0, stream>>>(wo, woT, DMODEL, DMODEL);

    // 1. Fused QKV projection: x @ wqkvT^T -> Q (out0) + K/V caches
    gemm_tn<float, 1><<<dim3((DMODEL + 2 * NKV * DHEAD) / 128, ROWS / 128), 256, 0, stream>>>(
        x, wqkvT, out, out_k, out_v, ROWS, DMODEL + 2 * NKV * DHEAD, DMODEL);
    // 2. RoPE in place on Q (with 1/8 scale) and K cache
    rope_f<<<(ROWS * 16 * 32) / 256, 256, 0, stream>>>(out, out_k);
    // 3. V^T bf16 prep
    vtransp<<<dim3(SEQ / 32, DHEAD / 32, BATCH * NKV), 256, 0, stream>>>(out_v, VtB);
    // 4. Flash attention -> ATTb (bf16)
    flash2<<<(BATCH * NHEADS) * (SEQ / 64), 256, 0, stream>>>(out, out_k, VtB, ATTb);
    // 5. Output projection: out <- ATTb @ woT^T
    gemm_tn<short, 0><<<dim3(DMODEL / 128, ROWS / 128), 256, 0, stream>>>(
        ATTb, woT, out, nullptr, nullptr, ROWS, DMODEL, DMODEL);
}

// Round 9
// 204.232 us; speedup vs baseline: 8.1265x; 1.1187x over previous
//
#include <hip/hip_runtime.h>
#include <hip/hip_bf16.h>

#define BATCH 2
#define SEQ 2048
#define DMODEL 768
#define NHEADS 12
#define NKV 4
#define DHEAD 64
#define WIN 512
#define GLB 64
#define ROWS (BATCH * SEQ)  // 4096

typedef short short8 __attribute__((ext_vector_type(8)));
typedef float f32x4 __attribute__((ext_vector_type(4)));

// fp32 -> bf16 bits, round-to-nearest-even (finite inputs only)
__device__ inline short f2bs(float f) {
    unsigned u = __float_as_uint(f);
    return (short)((u + 0x7fffu + ((u >> 16) & 1u)) >> 16);
}

// ---------------------------------------------------------------------------
// Transpose + bf16-convert: in[K,N] fp32 -> out[N,K] bf16 bits. 32x32 tiles.
// ---------------------------------------------------------------------------
__global__ __launch_bounds__(256) void transp(const float* __restrict__ in,
                                              short* __restrict__ out, int K, int N) {
    __shared__ float t[32][33];
    const int k0 = blockIdx.x * 32, n0 = blockIdx.y * 32;
    const int x = threadIdx.x & 31, y = threadIdx.x >> 5;  // y in [0,8)
#pragma unroll
    for (int i = 0; i < 32; i += 8)
        t[y + i][x] = in[(long)(k0 + y + i) * N + n0 + x];
    __syncthreads();
#pragma unroll
    for (int i = 0; i < 32; i += 8)
        out[(long)(n0 + y + i) * K + k0 + x] = f2bs(t[x][y + i]);
}

// ---------------------------------------------------------------------------
// V^T prep: out_v (B,NKV,SEQ,64) fp32 -> Vt (B,NKV,64,SEQ) bf16.
// ---------------------------------------------------------------------------
__global__ __launch_bounds__(256) void vtransp(const float* __restrict__ in,
                                               short* __restrict__ out) {
    __shared__ float t[32][33];
    const long bkv = blockIdx.z;
    const float* ip = in + bkv * SEQ * DHEAD;
    short* op = out + bkv * DHEAD * SEQ;
    const int t0 = blockIdx.x * 32, d0 = blockIdx.y * 32;
    const int x = threadIdx.x & 31, y = threadIdx.x >> 5;
#pragma unroll
    for (int i = 0; i < 32; i += 8)
        t[y + i][x] = ip[(long)(t0 + y + i) * DHEAD + d0 + x];
    __syncthreads();
#pragma unroll
    for (int i = 0; i < 32; i += 8)
        op[(long)(d0 + y + i) * SEQ + t0 + x] = f2bs(t[x][y + i]);
}

// ---------------------------------------------------------------------------
// MFMA GEMM (TN): C = A[M,K] @ Bt[N,K]^T, fp32 accumulate.
// TA = float (bf16-convert in staging) or short (raw bf16 bits).
// MODE 0: plain fp32 C.  MODE 1: 3-way split (Q row-major / K cache / V cache).
// 128x128 tile, BK=32; 4 waves 2x2, each 4x4 of 16x16x32 MFMA.
// ---------------------------------------------------------------------------
#define LST 40

template <typename TA, int MODE>
__global__ __launch_bounds__(256) void gemm_tn(const TA* __restrict__ A,
                                               const short* __restrict__ Bt,
                                               float* __restrict__ Cq,
                                               float* __restrict__ Ck,
                                               float* __restrict__ Cv,
                                               int M, int N, int K) {
    __shared__ short As_[128 * LST];
    __shared__ short Bs_[128 * LST];
    const int tid = threadIdx.x;
    const int lane = tid & 63, w = tid >> 6;
    const int m_ = lane & 15, quad = lane >> 4;
    const int wm = w >> 1, wn = w & 1;
    const long bm = (long)blockIdx.y * 128, bn = (long)blockIdx.x * 128;
    const int sr = tid >> 1, sh = (tid & 1) * 16;  // staging: row, k-half

    f32x4 acc[4][4];
#pragma unroll
    for (int i = 0; i < 4; ++i)
#pragma unroll
        for (int j = 0; j < 4; ++j) acc[i][j] = (f32x4){0.f, 0.f, 0.f, 0.f};

    for (int k0 = 0; k0 < K; k0 += 32) {
        short av[16], bv[16];
        if (sizeof(TA) == 4) {
            const float* ap = (const float*)A + (bm + sr) * K + k0 + sh;
            float ff[16];
#pragma unroll
            for (int i = 0; i < 4; ++i) *(float4*)&ff[4 * i] = ((const float4*)ap)[i];
#pragma unroll
            for (int i = 0; i < 16; ++i) av[i] = f2bs(ff[i]);
        } else {
            const short* ap = (const short*)A + (bm + sr) * K + k0 + sh;
            *(uint4*)&av[0] = ((const uint4*)ap)[0];
            *(uint4*)&av[8] = ((const uint4*)ap)[1];
        }
        {
            const short* bp = Bt + (bn + sr) * K + k0 + sh;
            *(uint4*)&bv[0] = ((const uint4*)bp)[0];
            *(uint4*)&bv[8] = ((const uint4*)bp)[1];
        }
        __syncthreads();
        short* ad = &As_[sr * LST + sh];
        short* bd = &Bs_[sr * LST + sh];
#pragma unroll
        for (int i = 0; i < 4; ++i) {
            ((uint2*)ad)[i] = ((uint2*)av)[i];
            ((uint2*)bd)[i] = ((uint2*)bv)[i];
        }
        __syncthreads();

        short8 af[4], bf[4];
#pragma unroll
        for (int i = 0; i < 4; ++i)
            af[i] = *(const short8*)&As_[(wm * 64 + i * 16 + m_) * LST + quad * 8];
#pragma unroll
        for (int j = 0; j < 4; ++j)
            bf[j] = *(const short8*)&Bs_[(wn * 64 + j * 16 + m_) * LST + quad * 8];
#pragma unroll
        for (int i = 0; i < 4; ++i)
#pragma unroll
            for (int j = 0; j < 4; ++j)
                acc[i][j] = __builtin_amdgcn_mfma_f32_16x16x32_bf16(af[i], bf[j], acc[i][j], 0, 0, 0);
    }

#pragma unroll
    for (int i = 0; i < 4; ++i) {
        const int row0 = (int)bm + wm * 64 + i * 16 + quad * 4;
#pragma unroll
        for (int j = 0; j < 4; ++j) {
            const int col = (int)bn + wn * 64 + j * 16 + m_;
#pragma unroll
            for (int r = 0; r < 4; ++r) {
                const int rw = row0 + r;
                const float val = acc[i][j][r];
                if (MODE == 1) {
                    if (col < DMODEL) {
                        Cq[(long)rw * DMODEL + col] = val;
                    } else {
                        const int c2 = col - DMODEL;        // 0..511
                        const int hh = (c2 >> 6) & 3, d = c2 & 63;
                        long oidx = (((long)((rw >> 11) * NKV + hh) * SEQ + (rw & (SEQ - 1))) << 6) | d;
                        ((c2 >> 8) ? Cv : Ck)[oidx] = val;
                    }
                } else {
                    Cq[(long)rw * N + col] = val;
                }
            }
        }
    }
}

// ---------------------------------------------------------------------------
// RoPE in place, fp32: Q ([ROWS,768], heads 0..11, folds 1/8 scale) and
// K cache ((B,4,SEQ,64), heads 12..15). K path ALSO writes bf16 copy Kb.
// ---------------------------------------------------------------------------
__global__ void rope_f(float* Qp, float* Kc, short* Kb) {
    int tid = blockIdx.x * blockDim.x + threadIdx.x;
    int j = tid & 31;
    int head = (tid >> 5) & 15;
    int row = tid >> 9;           // 0..4095
    int t = row & (SEQ - 1);
    int b = row >> 11;
    float inv = expf(-(float)j * 0.2878231366f);  // ln(10000)/32
    float s, c;
    sincosf((float)t * inv, &s, &c);
    if (head < NHEADS) {
        float* p = Qp + (long)row * DMODEL + head * DHEAD;
        float x1 = p[j], x2 = p[j + 32];
        p[j] = (x1 * c - x2 * s) * 0.125f;       // fold 1/sqrt(64)
        p[j + 32] = (x2 * c + x1 * s) * 0.125f;
    } else {
        const long off = ((long)(b * NKV + (head - NHEADS)) * SEQ + t) << 6;
        float* p = Kc + off;
        float x1 = p[j], x2 = p[j + 32];
        float y1 = x1 * c - x2 * s, y2 = x2 * c + x1 * s;
        p[j] = y1;
        p[j + 32] = y2;
        Kb[off + j] = f2bs(y1);
        Kb[off + j + 32] = f2bs(y2);
    }
}

// ---------------------------------------------------------------------------
// Flash attention v3: 64-key tiles, bf16 K/V direct global loads,
// K register double-buffer (prefetch next tile), all V issued at tile top.
// One wave = 16 Q rows; block = 64-row Q tile of one (b,h). Global key tile
// [0,64) FIRST (every row has key 0 allowed -> finite running max), then
// window tiles (64-aligned, >= 64 -> no overlap with global tile).
// P round-trip via per-wave LDS (validated R6-R8), stride 72 shorts
// (144 B = 16B-aligned rows, uniform bank spread).
// ---------------------------------------------------------------------------
#define PSTR 72

__global__ __launch_bounds__(256) void flash3(
    const float* __restrict__ Q, const short* __restrict__ Kb,
    const short* __restrict__ Vt, short* __restrict__ ATT) {
    __shared__ short Pl[4][16 * PSTR];
    const int tid = threadIdx.x;
    const int w = tid >> 6, lane = tid & 63;
    const int m_ = lane & 15, quad = lane >> 4;
    const int t0 = (blockIdx.x & 31) << 6;
    const int bh = blockIdx.x >> 5;       // b*12 + h
    const int b = bh / NHEADS, h = bh % NHEADS;
    const int kvh = h / (NHEADS / NKV);
    const long kbbase = ((long)(b * NKV + kvh) * SEQ) << 6;   // bf16 K cache
    const long vtbase = (long)(b * NKV + kvh) * DHEAD * SEQ;  // bf16 V^T
    const int trw = t0 + w * 16;          // wave's first Q row

    // Q A-frags (fp32 -> bf16 once)
    short8 qf[2];
    {
        const int qt = trw + m_;
        const float* qp = Q + (long)(b * SEQ + qt) * DMODEL + h * DHEAD + quad * 8;
        float4 a0 = *(const float4*)(qp);
        float4 a1 = *(const float4*)(qp + 4);
        float4 a2 = *(const float4*)(qp + 32);
        float4 a3 = *(const float4*)(qp + 36);
        short8 v0, v1;
        v0[0] = f2bs(a0.x); v0[1] = f2bs(a0.y); v0[2] = f2bs(a0.z); v0[3] = f2bs(a0.w);
        v0[4] = f2bs(a1.x); v0[5] = f2bs(a1.y); v0[6] = f2bs(a1.z); v0[7] = f2bs(a1.w);
        v1[0] = f2bs(a2.x); v1[1] = f2bs(a2.y); v1[2] = f2bs(a2.z); v1[3] = f2bs(a2.w);
        v1[4] = f2bs(a3.x); v1[5] = f2bs(a3.y); v1[6] = f2bs(a3.z); v1[7] = f2bs(a3.w);
        qf[0] = v0; qf[1] = v1;
    }

    f32x4 of[4];
#pragma unroll
    for (int i = 0; i < 4; ++i) of[i] = (f32x4){0.f, 0.f, 0.f, 0.f};
    float mr[4] = {-1e30f, -1e30f, -1e30f, -1e30f};
    float lr[4] = {0.f, 0.f, 0.f, 0.f};

    int wlo = t0 - (WIN - 1);
    if (wlo < GLB) wlo = GLB;
    wlo &= ~63;
    const int nwin = (t0 + 63 >= wlo) ? (((t0 + 63 - wlo) >> 6) + 1) : 0;
    const int ntile = 1 + nwin;

    short8 kcur[8], knext[8], vf[8];
    // preload K for tile 0 (kb=0): frag (st,hh): key kb+st*16+m_, d hh*32+quad*8
#pragma unroll
    for (int st = 0; st < 4; ++st)
#pragma unroll
        for (int hh = 0; hh < 2; ++hh)
            kcur[st * 2 + hh] = *(const short8*)(Kb + kbbase + ((long)(st * 16 + m_) << 6) + hh * 32 + quad * 8);

    for (int tI = 0; tI < ntile; ++tI) {
        const int kb = (tI == 0) ? 0 : (wlo + ((tI - 1) << 6));
        // issue ALL V loads for this tile (latency hidden behind QK+softmax)
#pragma unroll
        for (int dt = 0; dt < 4; ++dt)
#pragma unroll
            for (int kh = 0; kh < 2; ++kh)
                vf[dt * 2 + kh] = *(const short8*)(Vt + vtbase + (long)(dt * 16 + m_) * SEQ + kb + kh * 32 + quad * 8);
        // prefetch next tile's K
        if (tI + 1 < ntile) {
            const int kbn = (tI == 0) ? wlo : kb + 64;
#pragma unroll
            for (int st = 0; st < 4; ++st)
#pragma unroll
                for (int hh = 0; hh < 2; ++hh)
                    knext[st * 2 + hh] = *(const short8*)(Kb + kbbase + ((long)(kbn + st * 16 + m_) << 6) + hh * 32 + quad * 8);
        }

        // S = Q K^T over 64 keys (4 sub-tiles)
        f32x4 s[4];
#pragma unroll
        for (int st = 0; st < 4; ++st) {
            f32x4 a = (f32x4){0.f, 0.f, 0.f, 0.f};
            a = __builtin_amdgcn_mfma_f32_16x16x32_bf16(qf[0], kcur[st * 2 + 0], a, 0, 0, 0);
            a = __builtin_amdgcn_mfma_f32_16x16x32_bf16(qf[1], kcur[st * 2 + 1], a, 0, 0, 0);
            s[st] = a;
        }

        // mask unless tile fully allowed for this wave's 16 rows
        const bool fully = (kb + 63 <= trw) &&
                           ((kb >= trw + 16 - WIN) || (kb + 63 < GLB) || (trw + 15 < GLB));
        if (!fully) {
#pragma unroll
            for (int st = 0; st < 4; ++st) {
                const int key = kb + st * 16 + m_;
#pragma unroll
                for (int r = 0; r < 4; ++r) {
                    const int tq = trw + quad * 4 + r;
                    const bool ok = (key <= tq) && ((key > tq - WIN) || (key < GLB) || (tq < GLB));
                    if (!ok) s[st][r] = -1e30f;
                }
            }
        }

        // online softmax (per r; 16 col-lanes reduced via 4 xor-shuffles)
#pragma unroll
        for (int r = 0; r < 4; ++r) {
            float tm = fmaxf(fmaxf(s[0][r], s[1][r]), fmaxf(s[2][r], s[3][r]));
            tm = fmaxf(tm, __shfl_xor(tm, 1, 64));
            tm = fmaxf(tm, __shfl_xor(tm, 2, 64));
            tm = fmaxf(tm, __shfl_xor(tm, 4, 64));
            tm = fmaxf(tm, __shfl_xor(tm, 8, 64));
            const float mnew = fmaxf(mr[r], tm);
            const float alpha = __expf(mr[r] - mnew);
            mr[r] = mnew;
            float p[4];
#pragma unroll
            for (int st = 0; st < 4; ++st) p[st] = __expf(s[st][r] - mnew);
            float rs = (p[0] + p[1]) + (p[2] + p[3]);
            rs += __shfl_xor(rs, 1, 64);
            rs += __shfl_xor(rs, 2, 64);
            rs += __shfl_xor(rs, 4, 64);
            rs += __shfl_xor(rs, 8, 64);
            lr[r] = lr[r] * alpha + rs;
#pragma unroll
            for (int dt = 0; dt < 4; ++dt) of[dt][r] *= alpha;
            short* pr = &Pl[w][(quad * 4 + r) * PSTR + m_];
            pr[0] = f2bs(p[0]);
            pr[16] = f2bs(p[1]);
            pr[32] = f2bs(p[2]);
            pr[48] = f2bs(p[3]);
        }
        // P: C-layout -> A-layout via per-wave LDS
        short8 pf[2];
#pragma unroll
        for (int kh = 0; kh < 2; ++kh)
            pf[kh] = *(const short8*)&Pl[w][m_ * PSTR + kh * 32 + quad * 8];
        // O += P V (V already in flight since tile top)
#pragma unroll
        for (int dt = 0; dt < 4; ++dt) {
            of[dt] = __builtin_amdgcn_mfma_f32_16x16x32_bf16(pf[0], vf[dt * 2 + 0], of[dt], 0, 0, 0);
            of[dt] = __builtin_amdgcn_mfma_f32_16x16x32_bf16(pf[1], vf[dt * 2 + 1], of[dt], 0, 0, 0);
        }
#pragma unroll
        for (int i = 0; i < 8; ++i) kcur[i] = knext[i];
    }

#pragma unroll
    for (int r = 0; r < 4; ++r) {
        const int tq = trw + quad * 4 + r;
        const float inv = 1.0f / lr[r];
        short* op = ATT + (long)(b * SEQ + tq) * DMODEL + h * DHEAD + m_;
        op[0] = f2bs(of[0][r] * inv);
        op[16] = f2bs(of[1][r] * inv);
        op[32] = f2bs(of[2][r] * inv);
        op[48] = f2bs(of[3][r] * inv);
    }
}

// ---------------------------------------------------------------------------
extern "C" void kernel_launch(void* const* d_in, const int* in_sizes, int n_in,
                              void* d_out, int out_size, void* d_ws, size_t ws_size,
                              hipStream_t stream) {
    const float* x = (const float*)d_in[0];
    const float* wq = (const float*)d_in[1];
    const float* wk = (const float*)d_in[2];
    const float* wv = (const float*)d_in[3];
    const float* wo = (const float*)d_in[4];
    float* out = (float*)d_out;                               // [4096,768]: Q home, then final out
    float* out_k = out + (long)ROWS * DMODEL;                 // (B,4,SEQ,64) fp32
    float* out_v = out_k + (long)BATCH * NKV * SEQ * DHEAD;   // (B,4,SEQ,64) fp32

    // ws (shorts), 11.125 MiB total (< proven 12 MiB):
    //   [0, 3145728)        ATTb  -- ALSO wqkvT's home (dead before flash writes)
    //   [3145728, 3735552)  woT
    //   [3735552, 4784128)  Kb (bf16 rotated K cache)
    //   [4784128, 5832704)  Vt (bf16 V^T)
    short* ATTb = (short*)d_ws;
    short* wqkvT = ATTb;                                      // overlay (see above)
    short* woT = ATTb + (long)ROWS * DMODEL;
    short* KbB = woT + (long)DMODEL * DMODEL;
    short* VtB = KbB + (long)BATCH * NKV * SEQ * DHEAD;

    // 0. Transpose + bf16 weights
    transp<<<dim3(DMODEL / 32, DMODEL / 32), 256, 0, stream>>>(wq, wqkvT, DMODEL, DMODEL);
    transp<<<dim3(DMODEL / 32, (NKV * DHEAD) / 32), 256, 0, stream>>>(wk, wqkvT + (long)DMODEL * DMODEL, DMODEL, NKV * DHEAD);
    transp<<<dim3(DMODEL / 32, (NKV * DHEAD) / 32), 256, 0, stream>>>(wv, wqkvT + (long)(DMODEL + NKV * DHEAD) * DMODEL, DMODEL, NKV * DHEAD);
    transp<<<dim3(DMODEL / 32, DMODEL / 32), 256, 0, stream>>>(wo, woT, DMODEL, DMODEL);

    // 1. Fused QKV projection: x @ wqkvT^T -> Q (out0) + K/V caches (fp32)
    gemm_tn<float, 1><<<dim3((DMODEL + 2 * NKV * DHEAD) / 128, ROWS / 128), 256, 0, stream>>>(
        x, wqkvT, out, out_k, out_v, ROWS, DMODEL + 2 * NKV * DHEAD, DMODEL);
    // 2. RoPE in place (Q fp32 w/ 1/8 scale; K fp32 + bf16 copy Kb)
    rope_f<<<(ROWS * 16 * 32) / 256, 256, 0, stream>>>(out, out_k, KbB);
    // 3. V^T bf16 prep
    vtransp<<<dim3(SEQ / 32, DHEAD / 32, BATCH * NKV), 256, 0, stream>>>(out_v, VtB);
    // 4. Flash attention v3 -> ATTb (bf16)
    flash3<<<(BATCH * NHEADS) * (SEQ / 64), 256, 0, stream>>>(out, KbB, VtB, ATTb);
    // 5. Output projection: out <- ATTb @ woT^T
    gemm_tn<short, 0><<<dim3(DMODEL / 128, ROWS / 128), 256, 0, stream>>>(
        ATTb, woT, out, nullptr, nullptr, ROWS, DMODEL, DMODEL);
}

// Round 10
// 197.765 us; speedup vs baseline: 8.3922x; 1.0327x over previous
//
#include <hip/hip_runtime.h>
#include <hip/hip_bf16.h>

#define BATCH 2
#define SEQ 2048
#define DMODEL 768
#define NHEADS 12
#define NKV 4
#define DHEAD 64
#define WIN 512
#define GLB 64
#define ROWS (BATCH * SEQ)  // 4096

typedef short short8 __attribute__((ext_vector_type(8)));
typedef float f32x4 __attribute__((ext_vector_type(4)));

// fp32 -> bf16 bits, round-to-nearest-even (finite inputs only)
__device__ inline short f2bs(float f) {
    unsigned u = __float_as_uint(f);
    return (short)((u + 0x7fffu + ((u >> 16) & 1u)) >> 16);
}

// ---------------------------------------------------------------------------
// All four weight transposes in one launch: w[768,N] fp32 -> wT[N,768] bf16.
// Tile map: wq 576 | wk 192 | wv 192 | wo 576  (32x32 tiles, 256 thr)
// ---------------------------------------------------------------------------
__global__ __launch_bounds__(256) void transp_all(
    const float* __restrict__ wq, const float* __restrict__ wk,
    const float* __restrict__ wv, const float* __restrict__ wo,
    short* __restrict__ wqkvT, short* __restrict__ woT) {
    __shared__ float t[32][33];
    int bid = blockIdx.x;
    const float* src; short* dst; int N;
    if (bid < 576)      { src = wq; dst = wqkvT; N = DMODEL; }
    else if (bid < 768) { src = wk; dst = wqkvT + DMODEL * DMODEL; N = 256; bid -= 576; }
    else if (bid < 960) { src = wv; dst = wqkvT + (DMODEL + 256) * DMODEL; N = 256; bid -= 768; }
    else                { src = wo; dst = woT; N = DMODEL; bid -= 960; }
    const int ntx = N >> 5;
    const int k0 = (bid / ntx) << 5, n0 = (bid % ntx) << 5;
    const int x = threadIdx.x & 31, y = threadIdx.x >> 5;
#pragma unroll
    for (int i = 0; i < 32; i += 8)
        t[y + i][x] = src[(long)(k0 + y + i) * N + n0 + x];
    __syncthreads();
#pragma unroll
    for (int i = 0; i < 32; i += 8)
        dst[(long)(n0 + y + i) * DMODEL + k0 + x] = f2bs(t[x][y + i]);
}

// ---------------------------------------------------------------------------
// V^T prep: out_v (B,NKV,SEQ,64) fp32 -> Vt (B,NKV,64,SEQ) bf16.
// ---------------------------------------------------------------------------
__global__ __launch_bounds__(256) void vtransp(const float* __restrict__ in,
                                               short* __restrict__ out) {
    __shared__ float t[32][33];
    const long bkv = blockIdx.z;
    const float* ip = in + bkv * SEQ * DHEAD;
    short* op = out + bkv * DHEAD * SEQ;
    const int t0 = blockIdx.x * 32, d0 = blockIdx.y * 32;
    const int x = threadIdx.x & 31, y = threadIdx.x >> 5;
#pragma unroll
    for (int i = 0; i < 32; i += 8)
        t[y + i][x] = ip[(long)(t0 + y + i) * DHEAD + d0 + x];
    __syncthreads();
#pragma unroll
    for (int i = 0; i < 32; i += 8)
        op[(long)(d0 + y + i) * SEQ + t0 + x] = f2bs(t[x][y + i]);
}

// ---------------------------------------------------------------------------
// MFMA GEMM (TN): C = A[M,K] @ Bt[N,K]^T, fp32 accumulate.
// TA = float (bf16-convert in staging) or short (raw bf16 bits).
// MODE 0: plain fp32 C.  MODE 1: 3-way split (Q row-major / K cache / V cache).
// 128x128 tile, BK=32; 4 waves 2x2, each 4x4 of 16x16x32 MFMA.
// ---------------------------------------------------------------------------
#define LST 40

template <typename TA, int MODE>
__global__ __launch_bounds__(256) void gemm_tn(const TA* __restrict__ A,
                                               const short* __restrict__ Bt,
                                               float* __restrict__ Cq,
                                               float* __restrict__ Ck,
                                               float* __restrict__ Cv,
                                               int M, int N, int K) {
    __shared__ short As_[128 * LST];
    __shared__ short Bs_[128 * LST];
    const int tid = threadIdx.x;
    const int lane = tid & 63, w = tid >> 6;
    const int m_ = lane & 15, quad = lane >> 4;
    const int wm = w >> 1, wn = w & 1;
    const long bm = (long)blockIdx.y * 128, bn = (long)blockIdx.x * 128;
    const int sr = tid >> 1, sh = (tid & 1) * 16;  // staging: row, k-half

    f32x4 acc[4][4];
#pragma unroll
    for (int i = 0; i < 4; ++i)
#pragma unroll
        for (int j = 0; j < 4; ++j) acc[i][j] = (f32x4){0.f, 0.f, 0.f, 0.f};

    for (int k0 = 0; k0 < K; k0 += 32) {
        short av[16], bv[16];
        if (sizeof(TA) == 4) {
            const float* ap = (const float*)A + (bm + sr) * K + k0 + sh;
            float ff[16];
#pragma unroll
            for (int i = 0; i < 4; ++i) *(float4*)&ff[4 * i] = ((const float4*)ap)[i];
#pragma unroll
            for (int i = 0; i < 16; ++i) av[i] = f2bs(ff[i]);
        } else {
            const short* ap = (const short*)A + (bm + sr) * K + k0 + sh;
            *(uint4*)&av[0] = ((const uint4*)ap)[0];
            *(uint4*)&av[8] = ((const uint4*)ap)[1];
        }
        {
            const short* bp = Bt + (bn + sr) * K + k0 + sh;
            *(uint4*)&bv[0] = ((const uint4*)bp)[0];
            *(uint4*)&bv[8] = ((const uint4*)bp)[1];
        }
        __syncthreads();
        short* ad = &As_[sr * LST + sh];
        short* bd = &Bs_[sr * LST + sh];
#pragma unroll
        for (int i = 0; i < 4; ++i) {
            ((uint2*)ad)[i] = ((uint2*)av)[i];
            ((uint2*)bd)[i] = ((uint2*)bv)[i];
        }
        __syncthreads();

        short8 af[4], bf[4];
#pragma unroll
        for (int i = 0; i < 4; ++i)
            af[i] = *(const short8*)&As_[(wm * 64 + i * 16 + m_) * LST + quad * 8];
#pragma unroll
        for (int j = 0; j < 4; ++j)
            bf[j] = *(const short8*)&Bs_[(wn * 64 + j * 16 + m_) * LST + quad * 8];
#pragma unroll
        for (int i = 0; i < 4; ++i)
#pragma unroll
            for (int j = 0; j < 4; ++j)
                acc[i][j] = __builtin_amdgcn_mfma_f32_16x16x32_bf16(af[i], bf[j], acc[i][j], 0, 0, 0);
    }

#pragma unroll
    for (int i = 0; i < 4; ++i) {
        const int row0 = (int)bm + wm * 64 + i * 16 + quad * 4;
#pragma unroll
        for (int j = 0; j < 4; ++j) {
            const int col = (int)bn + wn * 64 + j * 16 + m_;
#pragma unroll
            for (int r = 0; r < 4; ++r) {
                const int rw = row0 + r;
                const float val = acc[i][j][r];
                if (MODE == 1) {
                    if (col < DMODEL) {
                        Cq[(long)rw * DMODEL + col] = val;
                    } else {
                        const int c2 = col - DMODEL;        // 0..511
                        const int hh = (c2 >> 6) & 3, d = c2 & 63;
                        long oidx = (((long)((rw >> 11) * NKV + hh) * SEQ + (rw & (SEQ - 1))) << 6) | d;
                        ((c2 >> 8) ? Cv : Ck)[oidx] = val;
                    }
                } else {
                    Cq[(long)rw * N + col] = val;
                }
            }
        }
    }
}

// ---------------------------------------------------------------------------
// RoPE: Q path reads fp32 Q (out0), writes bf16 Qb (w/ 1/8 scale folded).
// K path rotates fp32 K cache in place AND writes bf16 copy Kb.
// ---------------------------------------------------------------------------
__global__ void rope_f(const float* __restrict__ Qi, short* __restrict__ Qb,
                       float* Kc, short* Kb) {
    int tid = blockIdx.x * blockDim.x + threadIdx.x;
    int j = tid & 31;
    int head = (tid >> 5) & 15;
    int row = tid >> 9;           // 0..4095
    int t = row & (SEQ - 1);
    int b = row >> 11;
    float inv = expf(-(float)j * 0.2878231366f);  // ln(10000)/32
    float s, c;
    sincosf((float)t * inv, &s, &c);
    if (head < NHEADS) {
        const float* p = Qi + (long)row * DMODEL + head * DHEAD;
        short* q = Qb + (long)row * DMODEL + head * DHEAD;
        float x1 = p[j], x2 = p[j + 32];
        q[j] = f2bs((x1 * c - x2 * s) * 0.125f);       // fold 1/sqrt(64)
        q[j + 32] = f2bs((x2 * c + x1 * s) * 0.125f);
    } else {
        const long off = ((long)(b * NKV + (head - NHEADS)) * SEQ + t) << 6;
        float* p = Kc + off;
        float x1 = p[j], x2 = p[j + 32];
        float y1 = x1 * c - x2 * s, y2 = x2 * c + x1 * s;
        p[j] = y1;
        p[j + 32] = y2;
        Kb[off + j] = f2bs(y1);
        Kb[off + j + 32] = f2bs(y2);
    }
}

// ---------------------------------------------------------------------------
// Flash attention v4: TRANSPOSED dataflow. S^T = K Q^T (mfma(kf,qf)): lane
// col = q-row -> each lane owns 16 scores of ONE q-row; row max/sum are
// in-lane VALU + 2 shuffles (xor16/32 across quad replicas). m/l/alpha are
// per-lane scalars. O^T = V^T P^T (mfma(vf,pf)); epilogue scatter d-major.
// 64-key tiles; bf16 Q/K/V direct global loads (frag addresses unchanged
// from v3); P^T via per-wave LDS. Global tile [0,64) first (finite max).
// Heavy (large t0) blocks dispatch first. Qb lives in ATT region: each wave
// reads only its own rows before writing them (R4-proven in-place pattern).
// ---------------------------------------------------------------------------
#define PSTR 72

__global__ __launch_bounds__(256) void flash4(
    const short* __restrict__ Qb, const short* __restrict__ Kb,
    const short* __restrict__ Vt, short* __restrict__ ATT) {
    __shared__ short Pl[4][16 * PSTR];
    const int tid = threadIdx.x;
    const int w = tid >> 6, lane = tid & 63;
    const int m_ = lane & 15, quad = lane >> 4;
    const int t0 = (31 - (blockIdx.x & 31)) << 6;   // heavy blocks first
    const int bh = blockIdx.x >> 5;                 // b*12 + h
    const int b = bh / NHEADS, h = bh % NHEADS;
    const int kvh = h / (NHEADS / NKV);
    const long kbbase = ((long)(b * NKV + kvh) * SEQ) << 6;   // bf16 K cache
    const long vtbase = (long)(b * NKV + kvh) * DHEAD * SEQ;  // bf16 V^T
    const int trw = t0 + w * 16;   // wave's first Q row
    const int tq = trw + m_;       // THIS lane's q-row

    // Q B-frags, bf16 direct (B[n=q=m_][k=d=quad*8+i])
    const short* qp = Qb + (long)(b * SEQ + tq) * DMODEL + h * DHEAD + quad * 8;
    const short8 qf0 = *(const short8*)qp;
    const short8 qf1 = *(const short8*)(qp + 32);

    f32x4 of[4];
#pragma unroll
    for (int i = 0; i < 4; ++i) of[i] = (f32x4){0.f, 0.f, 0.f, 0.f};
    float mr = -1e30f, lr = 0.f;

    int wlo = t0 - (WIN - 1);
    if (wlo < GLB) wlo = GLB;
    wlo &= ~63;
    const int nwin = (t0 + 63 >= wlo) ? (((t0 + 63 - wlo) >> 6) + 1) : 0;
    const int ntile = 1 + nwin;

    for (int tI = 0; tI < ntile; ++tI) {
        const int kb = (tI == 0) ? 0 : (wlo + ((tI - 1) << 6));

        // K A-frags (A[m=key=st*16+m_][k=d=hh*32+quad*8]) + V A-frags
        short8 kf[8], vf[8];
#pragma unroll
        for (int st = 0; st < 4; ++st)
#pragma unroll
            for (int hh = 0; hh < 2; ++hh)
                kf[st * 2 + hh] = *(const short8*)(Kb + kbbase + ((long)(kb + st * 16 + m_) << 6) + hh * 32 + quad * 8);
#pragma unroll
        for (int dt = 0; dt < 4; ++dt)
#pragma unroll
            for (int kh = 0; kh < 2; ++kh)
                vf[dt * 2 + kh] = *(const short8*)(Vt + vtbase + (long)(dt * 16 + m_) * SEQ + kb + kh * 32 + quad * 8);

        // S^T = K Q^T : lane holds scores for q-row tq, keys kb+st*16+quad*4+r
        f32x4 s[4];
#pragma unroll
        for (int st = 0; st < 4; ++st) {
            f32x4 a = (f32x4){0.f, 0.f, 0.f, 0.f};
            a = __builtin_amdgcn_mfma_f32_16x16x32_bf16(kf[st * 2 + 0], qf0, a, 0, 0, 0);
            a = __builtin_amdgcn_mfma_f32_16x16x32_bf16(kf[st * 2 + 1], qf1, a, 0, 0, 0);
            s[st] = a;
        }

        // mask unless tile fully allowed for this wave's 16 rows
        const bool fully = (kb + 63 <= trw) &&
                           ((kb >= trw + 16 - WIN) || (kb + 63 < GLB) || (trw + 15 < GLB));
        if (!fully) {
#pragma unroll
            for (int st = 0; st < 4; ++st) {
#pragma unroll
                for (int r = 0; r < 4; ++r) {
                    const int key = kb + st * 16 + quad * 4 + r;
                    const bool ok = (key <= tq) && ((key > tq - WIN) || (key < GLB) || (tq < GLB));
                    if (!ok) s[st][r] = -1e30f;
                }
            }
        }

        // online softmax: in-lane tree + 2 shuffles (quad replicas)
        float tm = -1e30f;
#pragma unroll
        for (int st = 0; st < 4; ++st)
#pragma unroll
            for (int r = 0; r < 4; ++r) tm = fmaxf(tm, s[st][r]);
        tm = fmaxf(tm, __shfl_xor(tm, 16, 64));
        tm = fmaxf(tm, __shfl_xor(tm, 32, 64));
        const float mnew = fmaxf(mr, tm);
        const float alpha = __expf(mr - mnew);
        mr = mnew;
        float rs = 0.f;
#pragma unroll
        for (int st = 0; st < 4; ++st) {
            float p0 = __expf(s[st][0] - mnew);
            float p1 = __expf(s[st][1] - mnew);
            float p2 = __expf(s[st][2] - mnew);
            float p3 = __expf(s[st][3] - mnew);
            rs += (p0 + p1) + (p2 + p3);
            union { short sh[4]; unsigned long long u; } pk;
            pk.sh[0] = f2bs(p0); pk.sh[1] = f2bs(p1);
            pk.sh[2] = f2bs(p2); pk.sh[3] = f2bs(p3);
            *(unsigned long long*)&Pl[w][m_ * PSTR + st * 16 + quad * 4] = pk.u;
        }
        rs += __shfl_xor(rs, 16, 64);
        rs += __shfl_xor(rs, 32, 64);
        lr = lr * alpha + rs;
#pragma unroll
        for (int dt = 0; dt < 4; ++dt)
#pragma unroll
            for (int r = 0; r < 4; ++r) of[dt][r] *= alpha;

        // P^T B-frags from LDS (B[n=q=m_][k=key=kh*32+quad*8+i])
        short8 pf[2];
#pragma unroll
        for (int kh = 0; kh < 2; ++kh)
            pf[kh] = *(const short8*)&Pl[w][m_ * PSTR + kh * 32 + quad * 8];

        // O^T += V^T P^T
#pragma unroll
        for (int dt = 0; dt < 4; ++dt) {
            of[dt] = __builtin_amdgcn_mfma_f32_16x16x32_bf16(vf[dt * 2 + 0], pf[0], of[dt], 0, 0, 0);
            of[dt] = __builtin_amdgcn_mfma_f32_16x16x32_bf16(vf[dt * 2 + 1], pf[1], of[dt], 0, 0, 0);
        }
    }

    // epilogue: lane owns q-row tq; d = dt*16 + quad*4 + r (4 packed stores)
    const float inv = 1.0f / lr;
    short* op = ATT + (long)(b * SEQ + tq) * DMODEL + h * DHEAD + quad * 4;
#pragma unroll
    for (int dt = 0; dt < 4; ++dt) {
        union { short sh[4]; unsigned long long u; } pk;
#pragma unroll
        for (int r = 0; r < 4; ++r) pk.sh[r] = f2bs(of[dt][r] * inv);
        *(unsigned long long*)(op + dt * 16) = pk.u;
    }
}

// ---------------------------------------------------------------------------
extern "C" void kernel_launch(void* const* d_in, const int* in_sizes, int n_in,
                              void* d_out, int out_size, void* d_ws, size_t ws_size,
                              hipStream_t stream) {
    const float* x = (const float*)d_in[0];
    const float* wq = (const float*)d_in[1];
    const float* wk = (const float*)d_in[2];
    const float* wv = (const float*)d_in[3];
    const float* wo = (const float*)d_in[4];
    float* out = (float*)d_out;                               // [4096,768]: fp32 Q home, then final out
    float* out_k = out + (long)ROWS * DMODEL;                 // (B,4,SEQ,64) fp32
    float* out_v = out_k + (long)BATCH * NKV * SEQ * DHEAD;   // (B,4,SEQ,64) fp32

    // ws (shorts), 11.125 MiB:
    //   [0, 3145728)        region A: wqkvT (dead after QKV gemm) -> Qb (bf16)
    //                       -> ATTb (flash writes over its own Qb rows)
    //   [3145728, 3735552)  woT
    //   [3735552, 4784128)  Kb (bf16 rotated K cache)
    //   [4784128, 5832704)  Vt (bf16 V^T)
    short* regA = (short*)d_ws;
    short* wqkvT = regA;
    short* Qb = regA;
    short* ATTb = regA;
    short* woT = regA + (long)ROWS * DMODEL;
    short* KbB = woT + (long)DMODEL * DMODEL;
    short* VtB = KbB + (long)BATCH * NKV * SEQ * DHEAD;

    // 0. All weight transposes (one launch)
    transp_all<<<1536, 256, 0, stream>>>(wq, wk, wv, wo, wqkvT, woT);
    // 1. Fused QKV projection: x @ wqkvT^T -> Q fp32 (out0) + K/V caches (fp32)
    gemm_tn<float, 1><<<dim3((DMODEL + 2 * NKV * DHEAD) / 128, ROWS / 128), 256, 0, stream>>>(
        x, wqkvT, out, out_k, out_v, ROWS, DMODEL + 2 * NKV * DHEAD, DMODEL);
    // 2. RoPE: Q fp32 -> Qb bf16 (1/8 scale); K fp32 in place + bf16 Kb
    rope_f<<<(ROWS * 16 * 32) / 256, 256, 0, stream>>>(out, Qb, out_k, KbB);
    // 3. V^T bf16 prep
    vtransp<<<dim3(SEQ / 32, DHEAD / 32, BATCH * NKV), 256, 0, stream>>>(out_v, VtB);
    // 4. Flash attention v4 (transposed dataflow) -> ATTb (bf16, over Qb)
    flash4<<<(BATCH * NHEADS) * (SEQ / 64), 256, 0, stream>>>(Qb, KbB, VtB, ATTb);
    // 5. Output projection: out <- ATTb @ woT^T
    gemm_tn<short, 0><<<dim3(DMODEL / 128, ROWS / 128), 256, 0, stream>>>(
        ATTb, woT, out, nullptr, nullptr, ROWS, DMODEL, DMODEL);
}

// Round 12
// 186.999 us; speedup vs baseline: 8.8754x; 1.0576x over previous
//
#include <hip/hip_runtime.h>
#include <hip/hip_bf16.h>

#define BATCH 2
#define SEQ 2048
#define DMODEL 768
#define NHEADS 12
#define NKV 4
#define DHEAD 64
#define WIN 512
#define GLB 64
#define ROWS (BATCH * SEQ)  // 4096

typedef short short8 __attribute__((ext_vector_type(8)));
typedef float f32x4 __attribute__((ext_vector_type(4)));

// fp32 -> bf16 bits, round-to-nearest-even (finite inputs only)
__device__ inline short f2bs(float f) {
    unsigned u = __float_as_uint(f);
    return (short)((u + 0x7fffu + ((u >> 16) & 1u)) >> 16);
}

// ---------------------------------------------------------------------------
// All four weight transposes in one launch: w[768,N] fp32 -> wT[N,768] bf16.
// ---------------------------------------------------------------------------
__global__ __launch_bounds__(256) void transp_all(
    const float* __restrict__ wq, const float* __restrict__ wk,
    const float* __restrict__ wv, const float* __restrict__ wo,
    short* __restrict__ wqkvT, short* __restrict__ woT) {
    __shared__ float t[32][33];
    int bid = blockIdx.x;
    const float* src; short* dst; int N;
    if (bid < 576)      { src = wq; dst = wqkvT; N = DMODEL; }
    else if (bid < 768) { src = wk; dst = wqkvT + DMODEL * DMODEL; N = 256; bid -= 576; }
    else if (bid < 960) { src = wv; dst = wqkvT + (DMODEL + 256) * DMODEL; N = 256; bid -= 768; }
    else                { src = wo; dst = woT; N = DMODEL; bid -= 960; }
    const int ntx = N >> 5;
    const int k0 = (bid / ntx) << 5, n0 = (bid % ntx) << 5;
    const int x = threadIdx.x & 31, y = threadIdx.x >> 5;
#pragma unroll
    for (int i = 0; i < 32; i += 8)
        t[y + i][x] = src[(long)(k0 + y + i) * N + n0 + x];
    __syncthreads();
#pragma unroll
    for (int i = 0; i < 32; i += 8)
        dst[(long)(n0 + y + i) * DMODEL + k0 + x] = f2bs(t[x][y + i]);
}

// ---------------------------------------------------------------------------
// V^T prep, PANELED: out_v (B,NKV,SEQ,64) fp32 ->
// Vt[bkv][t>>6][d][t&63] bf16 (each 64-key panel = 8 KB contiguous).
// ---------------------------------------------------------------------------
__global__ __launch_bounds__(256) void vtransp(const float* __restrict__ in,
                                               short* __restrict__ out) {
    __shared__ float t[32][33];
    const long bkv = blockIdx.z;
    const float* ip = in + bkv * SEQ * DHEAD;
    short* op = out + bkv * DHEAD * SEQ;
    const int t0 = blockIdx.x * 32, d0 = blockIdx.y * 32;
    const int x = threadIdx.x & 31, y = threadIdx.x >> 5;
#pragma unroll
    for (int i = 0; i < 32; i += 8)
        t[y + i][x] = ip[(long)(t0 + y + i) * DHEAD + d0 + x];
    __syncthreads();
    const int pan = t0 >> 6, tin = t0 & 63;  // uniform for x<32
#pragma unroll
    for (int i = 0; i < 32; i += 8)
        op[(long)pan * 4096 + (d0 + y + i) * 64 + tin + x] = f2bs(t[x][y + i]);
}

// ---------------------------------------------------------------------------
// MFMA GEMM (TN): C = A[M,K] @ Bt[N,K]^T, fp32 accumulate.
// MODE 0: plain fp32 C.  MODE 1: 3-way split (Q / K cache / V cache).
// ---------------------------------------------------------------------------
#define LST 40

template <typename TA, int MODE>
__global__ __launch_bounds__(256) void gemm_tn(const TA* __restrict__ A,
                                               const short* __restrict__ Bt,
                                               float* __restrict__ Cq,
                                               float* __restrict__ Ck,
                                               float* __restrict__ Cv,
                                               int M, int N, int K) {
    __shared__ short As_[128 * LST];
    __shared__ short Bs_[128 * LST];
    const int tid = threadIdx.x;
    const int lane = tid & 63, w = tid >> 6;
    const int m_ = lane & 15, quad = lane >> 4;
    const int wm = w >> 1, wn = w & 1;
    const long bm = (long)blockIdx.y * 128, bn = (long)blockIdx.x * 128;
    const int sr = tid >> 1, sh = (tid & 1) * 16;

    f32x4 acc[4][4];
#pragma unroll
    for (int i = 0; i < 4; ++i)
#pragma unroll
        for (int j = 0; j < 4; ++j) acc[i][j] = (f32x4){0.f, 0.f, 0.f, 0.f};

    for (int k0 = 0; k0 < K; k0 += 32) {
        short av[16], bv[16];
        if (sizeof(TA) == 4) {
            const float* ap = (const float*)A + (bm + sr) * K + k0 + sh;
            float ff[16];
#pragma unroll
            for (int i = 0; i < 4; ++i) *(float4*)&ff[4 * i] = ((const float4*)ap)[i];
#pragma unroll
            for (int i = 0; i < 16; ++i) av[i] = f2bs(ff[i]);
        } else {
            const short* ap = (const short*)A + (bm + sr) * K + k0 + sh;
            *(uint4*)&av[0] = ((const uint4*)ap)[0];
            *(uint4*)&av[8] = ((const uint4*)ap)[1];
        }
        {
            const short* bp = Bt + (bn + sr) * K + k0 + sh;
            *(uint4*)&bv[0] = ((const uint4*)bp)[0];
            *(uint4*)&bv[8] = ((const uint4*)bp)[1];
        }
        __syncthreads();
        short* ad = &As_[sr * LST + sh];
        short* bd = &Bs_[sr * LST + sh];
#pragma unroll
        for (int i = 0; i < 4; ++i) {
            ((uint2*)ad)[i] = ((uint2*)av)[i];
            ((uint2*)bd)[i] = ((uint2*)bv)[i];
        }
        __syncthreads();

        short8 af[4], bf[4];
#pragma unroll
        for (int i = 0; i < 4; ++i)
            af[i] = *(const short8*)&As_[(wm * 64 + i * 16 + m_) * LST + quad * 8];
#pragma unroll
        for (int j = 0; j < 4; ++j)
            bf[j] = *(const short8*)&Bs_[(wn * 64 + j * 16 + m_) * LST + quad * 8];
#pragma unroll
        for (int i = 0; i < 4; ++i)
#pragma unroll
            for (int j = 0; j < 4; ++j)
                acc[i][j] = __builtin_amdgcn_mfma_f32_16x16x32_bf16(af[i], bf[j], acc[i][j], 0, 0, 0);
    }

#pragma unroll
    for (int i = 0; i < 4; ++i) {
        const int row0 = (int)bm + wm * 64 + i * 16 + quad * 4;
#pragma unroll
        for (int j = 0; j < 4; ++j) {
            const int col = (int)bn + wn * 64 + j * 16 + m_;
#pragma unroll
            for (int r = 0; r < 4; ++r) {
                const int rw = row0 + r;
                const float val = acc[i][j][r];
                if (MODE == 1) {
                    if (col < DMODEL) {
                        Cq[(long)rw * DMODEL + col] = val;
                    } else {
                        const int c2 = col - DMODEL;
                        const int hh = (c2 >> 6) & 3, d = c2 & 63;
                        long oidx = (((long)((rw >> 11) * NKV + hh) * SEQ + (rw & (SEQ - 1))) << 6) | d;
                        ((c2 >> 8) ? Cv : Ck)[oidx] = val;
                    }
                } else {
                    Cq[(long)rw * N + col] = val;
                }
            }
        }
    }
}

// ---------------------------------------------------------------------------
// RoPE: Q fp32 -> bf16 Qb (1/8 scale); K fp32 in place + bf16 copy Kb.
// ---------------------------------------------------------------------------
__global__ void rope_f(const float* __restrict__ Qi, short* __restrict__ Qb,
                       float* Kc, short* Kb) {
    int tid = blockIdx.x * blockDim.x + threadIdx.x;
    int j = tid & 31;
    int head = (tid >> 5) & 15;
    int row = tid >> 9;
    int t = row & (SEQ - 1);
    int b = row >> 11;
    float inv = expf(-(float)j * 0.2878231366f);
    float s, c;
    sincosf((float)t * inv, &s, &c);
    if (head < NHEADS) {
        const float* p = Qi + (long)row * DMODEL + head * DHEAD;
        short* q = Qb + (long)row * DMODEL + head * DHEAD;
        float x1 = p[j], x2 = p[j + 32];
        q[j] = f2bs((x1 * c - x2 * s) * 0.125f);
        q[j + 32] = f2bs((x2 * c + x1 * s) * 0.125f);
    } else {
        const long off = ((long)(b * NKV + (head - NHEADS)) * SEQ + t) << 6;
        float* p = Kc + off;
        float x1 = p[j], x2 = p[j + 32];
        float y1 = x1 * c - x2 * s, y2 = x2 * c + x1 * s;
        p[j] = y1;
        p[j + 32] = y2;
        Kb[off + j] = f2bs(y1);
        Kb[off + j + 32] = f2bs(y2);
    }
}

// ---------------------------------------------------------------------------
// Flash v6 (fixed): GQA-merged LDS-staged. Block = (b,kvh, 32 q-rows) x 3
// heads: 6 waves. K/V 64-key panels staged to LDS once per block per tile,
// padded stride 72 shorts. Pipeline: load(i+1) -> compute(i) -> write(i+1)
// -> barrier. Transposed softmax dataflow (S^T = K Q^T; per-lane m/l).
// R11 BUG FIX: wlo uses FIRST row's window floor t0-(WIN-1), not last row's.
// ---------------------------------------------------------------------------
#define KST 72

__global__ __launch_bounds__(384) void flash6(
    const short* __restrict__ Qb, const short* __restrict__ Kb,
    const short* __restrict__ Vt, short* __restrict__ ATT) {
    __shared__ short Kbuf[2][64 * KST];
    __shared__ short Vbuf[2][64 * KST];
    __shared__ short Pl[6][16 * KST];
    const int tid = threadIdx.x;
    const int w = tid >> 6, lane = tid & 63;
    const int m_ = lane & 15, quad = lane >> 4;
    const int bkv = blockIdx.x >> 6;
    const int t0 = (63 - (blockIdx.x & 63)) << 5;   // heavy blocks first
    const int b = bkv >> 2, kvh = bkv & 3;
    const int h = kvh * 3 + (w >> 1);
    const int qg = w & 1;
    const int trw = t0 + (qg << 4);
    const int tq = trw + m_;       // this lane's q-row
    const long kgb = ((long)bkv * SEQ) << 6;        // Kb base (shorts)
    const long vgb = (long)bkv * SEQ * DHEAD;       // Vt base (shorts)

    // Q B-frags
    const short* qp = Qb + (long)(b * SEQ + tq) * DMODEL + h * DHEAD + quad * 8;
    const short8 qf0 = *(const short8*)qp;
    const short8 qf1 = *(const short8*)(qp + 32);

    f32x4 of[4];
#pragma unroll
    for (int i = 0; i < 4; ++i) of[i] = (f32x4){0.f, 0.f, 0.f, 0.f};
    float mr = -1e30f, lr = 0.f;

    int wlo = t0 - (WIN - 1);      // FIRST row's window floor (R11 bug fix)
    if (wlo < GLB) wlo = GLB;
    wlo &= ~63;
    const int nwin = (t0 + 31 >= wlo) ? (((t0 + 31 - wlo) >> 6) + 1) : 0;
    const int ntile = 1 + nwin;

    // staging: 1024 uint4 items (K 512 | V 512); 384 thr x <=3 rounds
    uint4 sreg[3];
    int sidx[3], scnt = 0;
#pragma unroll
    for (int r = 0; r < 3; ++r) {
        int idx = tid + r * 384;
        if (idx < 1024) sidx[scnt++] = idx;
    }
    auto stage_load = [&](int kb) {
        const short* kp = Kb + kgb + ((long)kb << 6);
        const short* vp = Vt + vgb + ((long)(kb >> 6) << 12);
        for (int r = 0; r < scnt; ++r) {
            int idx = sidx[r];
            if (idx < 512) sreg[r] = *(const uint4*)(kp + ((idx >> 3) << 6) + ((idx & 7) << 3));
            else { int i2 = idx - 512; sreg[r] = *(const uint4*)(vp + ((i2 >> 3) << 6) + ((i2 & 7) << 3)); }
        }
    };
    auto stage_write = [&](int bs) {
        for (int r = 0; r < scnt; ++r) {
            int idx = sidx[r];
            if (idx < 512) *(uint4*)(&Kbuf[bs][(idx >> 3) * KST + ((idx & 7) << 3)]) = sreg[r];
            else { int i2 = idx - 512; *(uint4*)(&Vbuf[bs][(i2 >> 3) * KST + ((i2 & 7) << 3)]) = sreg[r]; }
        }
    };

    stage_load(0);
    stage_write(0);
    __syncthreads();

    for (int tI = 0; tI < ntile; ++tI) {
        const int kb = (tI == 0) ? 0 : (wlo + ((tI - 1) << 6));
        if (tI + 1 < ntile) stage_load((tI == 0) ? wlo : kb + 64);
        const int bs = tI & 1;

        // frags from LDS
        short8 kf[8], vf[8];
#pragma unroll
        for (int st = 0; st < 4; ++st)
#pragma unroll
            for (int hh = 0; hh < 2; ++hh)
                kf[st * 2 + hh] = *(const short8*)&Kbuf[bs][(st * 16 + m_) * KST + hh * 32 + quad * 8];
#pragma unroll
        for (int dt = 0; dt < 4; ++dt)
#pragma unroll
            for (int kh = 0; kh < 2; ++kh)
                vf[dt * 2 + kh] = *(const short8*)&Vbuf[bs][(dt * 16 + m_) * KST + kh * 32 + quad * 8];

        // S^T = K Q^T
        f32x4 s[4];
#pragma unroll
        for (int st = 0; st < 4; ++st) {
            f32x4 a = (f32x4){0.f, 0.f, 0.f, 0.f};
            a = __builtin_amdgcn_mfma_f32_16x16x32_bf16(kf[st * 2 + 0], qf0, a, 0, 0, 0);
            a = __builtin_amdgcn_mfma_f32_16x16x32_bf16(kf[st * 2 + 1], qf1, a, 0, 0, 0);
            s[st] = a;
        }

        const bool fully = (kb + 63 <= trw) &&
                           ((kb >= trw + 16 - WIN) || (kb + 63 < GLB) || (trw + 15 < GLB));
        if (!fully) {
#pragma unroll
            for (int st = 0; st < 4; ++st) {
#pragma unroll
                for (int r = 0; r < 4; ++r) {
                    const int key = kb + st * 16 + quad * 4 + r;
                    const bool ok = (key <= tq) && ((key > tq - WIN) || (key < GLB) || (tq < GLB));
                    if (!ok) s[st][r] = -1e30f;
                }
            }
        }

        // online softmax (per-lane; 2 shuffles across quad replicas)
        float tm = -1e30f;
#pragma unroll
        for (int st = 0; st < 4; ++st)
#pragma unroll
            for (int r = 0; r < 4; ++r) tm = fmaxf(tm, s[st][r]);
        tm = fmaxf(tm, __shfl_xor(tm, 16, 64));
        tm = fmaxf(tm, __shfl_xor(tm, 32, 64));
        const float mnew = fmaxf(mr, tm);
        const float alpha = __expf(mr - mnew);
        mr = mnew;
        float rs = 0.f;
#pragma unroll
        for (int st = 0; st < 4; ++st) {
            float p0 = __expf(s[st][0] - mnew);
            float p1 = __expf(s[st][1] - mnew);
            float p2 = __expf(s[st][2] - mnew);
            float p3 = __expf(s[st][3] - mnew);
            rs += (p0 + p1) + (p2 + p3);
            union { short sh[4]; unsigned long long u; } pk;
            pk.sh[0] = f2bs(p0); pk.sh[1] = f2bs(p1);
            pk.sh[2] = f2bs(p2); pk.sh[3] = f2bs(p3);
            *(unsigned long long*)&Pl[w][m_ * KST + st * 16 + quad * 4] = pk.u;
        }
        rs += __shfl_xor(rs, 16, 64);
        rs += __shfl_xor(rs, 32, 64);
        lr = lr * alpha + rs;
#pragma unroll
        for (int dt = 0; dt < 4; ++dt)
#pragma unroll
            for (int r = 0; r < 4; ++r) of[dt][r] *= alpha;

        // P^T B-frags via per-wave LDS
        short8 pf[2];
#pragma unroll
        for (int kh = 0; kh < 2; ++kh)
            pf[kh] = *(const short8*)&Pl[w][m_ * KST + kh * 32 + quad * 8];

        // O^T += V^T P^T
#pragma unroll
        for (int dt = 0; dt < 4; ++dt) {
            of[dt] = __builtin_amdgcn_mfma_f32_16x16x32_bf16(vf[dt * 2 + 0], pf[0], of[dt], 0, 0, 0);
            of[dt] = __builtin_amdgcn_mfma_f32_16x16x32_bf16(vf[dt * 2 + 1], pf[1], of[dt], 0, 0, 0);
        }

        if (tI + 1 < ntile) stage_write((tI + 1) & 1);
        __syncthreads();
    }

    // epilogue
    const float inv = 1.0f / lr;
    short* op = ATT + (long)(b * SEQ + tq) * DMODEL + h * DHEAD + quad * 4;
#pragma unroll
    for (int dt = 0; dt < 4; ++dt) {
        union { short sh[4]; unsigned long long u; } pk;
#pragma unroll
        for (int r = 0; r < 4; ++r) pk.sh[r] = f2bs(of[dt][r] * inv);
        *(unsigned long long*)(op + dt * 16) = pk.u;
    }
}

// ---------------------------------------------------------------------------
extern "C" void kernel_launch(void* const* d_in, const int* in_sizes, int n_in,
                              void* d_out, int out_size, void* d_ws, size_t ws_size,
                              hipStream_t stream) {
    const float* x = (const float*)d_in[0];
    const float* wq = (const float*)d_in[1];
    const float* wk = (const float*)d_in[2];
    const float* wv = (const float*)d_in[3];
    const float* wo = (const float*)d_in[4];
    float* out = (float*)d_out;
    float* out_k = out + (long)ROWS * DMODEL;
    float* out_v = out_k + (long)BATCH * NKV * SEQ * DHEAD;

    // ws (shorts), 11.125 MiB: region A: wqkvT -> Qb -> ATTb (sequential lifetimes)
    short* regA = (short*)d_ws;
    short* wqkvT = regA;
    short* Qb = regA;
    short* ATTb = regA;
    short* woT = regA + (long)ROWS * DMODEL;
    short* KbB = woT + (long)DMODEL * DMODEL;
    short* VtB = KbB + (long)BATCH * NKV * SEQ * DHEAD;

    transp_all<<<1536, 256, 0, stream>>>(wq, wk, wv, wo, wqkvT, woT);
    gemm_tn<float, 1><<<dim3((DMODEL + 2 * NKV * DHEAD) / 128, ROWS / 128), 256, 0, stream>>>(
        x, wqkvT, out, out_k, out_v, ROWS, DMODEL + 2 * NKV * DHEAD, DMODEL);
    rope_f<<<(ROWS * 16 * 32) / 256, 256, 0, stream>>>(out, Qb, out_k, KbB);
    vtransp<<<dim3(SEQ / 32, DHEAD / 32, BATCH * NKV), 256, 0, stream>>>(out_v, VtB);
    flash6<<<BATCH * NKV * (SEQ / 32), 384, 0, stream>>>(Qb, KbB, VtB, ATTb);
    gemm_tn<short, 0><<<dim3(DMODEL / 128, ROWS / 128), 256, 0, stream>>>(
        ATTb, woT, out, nullptr, nullptr, ROWS, DMODEL, DMODEL);
}